// Round 1
// baseline (2434.524 us; speedup 1.0000x reference)
//
#include <hip/hip_runtime.h>
#include <math.h>

// ---------------------------------------------------------------------------
// Fused transformer block on MI355X.
// Precision strategy: everything that feeds the MoE router (rmsnorm1, QKV,
// RoPE, attention, out-proj, rmsnorm2, logits) is computed in fp32 vector math
// so top-2 expert decisions match the numpy fp32 reference (min logit gap over
// 4096 tokens ~4e-5; bf16 there would flip ~60 tokens and blow the 0.104
// threshold). Post-routing MoE GEMMs use bf16 MFMA (error ~4e-4, harmless).
// ---------------------------------------------------------------------------

#define B_   2
#define S_   2048
#define D_   1024
#define H_   16
#define HD_  64
#define FFN_ 2048
#define E_   8
#define CAP_ 1280
#define T_   (B_*S_)

typedef unsigned short u16;
typedef __attribute__((ext_vector_type(8))) short     short8;    // MFMA bf16x8 operand
typedef __attribute__((ext_vector_type(8))) unsigned short ushort8v;
typedef __attribute__((ext_vector_type(4))) float     f32x4;

__device__ __forceinline__ u16 f2bf(float f) {
  unsigned u = __float_as_uint(f);
  return (u16)((u + 0x7fffu + ((u >> 16) & 1u)) >> 16);   // RNE
}

__device__ __forceinline__ void cstore(float* p, float v) { *p = v; }
__device__ __forceinline__ void cstore(u16* p, float v)   { *p = f2bf(v); }

// --------------------------- init: zero expert counters --------------------
__global__ void init_k(int* cnt) {
  if (threadIdx.x < 16) cnt[threadIdx.x] = 0;
}

// --------------------------- RMSNorm (fp32 in, fp32 + optional bf16 out) ---
__global__ __launch_bounds__(256) void rmsnorm_k(const float* __restrict__ x,
                                                 const float* __restrict__ g,
                                                 float* __restrict__ of,
                                                 u16*   __restrict__ ob) {
  const int t = blockIdx.x, tid = threadIdx.x;
  const float4 xv = ((const float4*)(x + (size_t)t * D_))[tid];
  float ss = xv.x*xv.x + xv.y*xv.y + xv.z*xv.z + xv.w*xv.w;
  #pragma unroll
  for (int off = 32; off; off >>= 1) ss += __shfl_down(ss, off);
  __shared__ float wsum[4];
  if ((tid & 63) == 0) wsum[tid >> 6] = ss;
  __syncthreads();
  const float tot = wsum[0] + wsum[1] + wsum[2] + wsum[3];
  const float rms = 1.0f / sqrtf(tot * (1.0f / D_) + 1e-6f);
  const float4 gv = ((const float4*)g)[tid];
  float4 o;
  o.x = gv.x * xv.x * rms;
  o.y = gv.y * xv.y * rms;
  o.z = gv.z * xv.z * rms;
  o.w = gv.w * xv.w * rms;
  if (of) ((float4*)(of + (size_t)t * D_))[tid] = o;
  if (ob) {
    ushort4 h;
    h.x = f2bf(o.x); h.y = f2bf(o.y); h.z = f2bf(o.z); h.w = f2bf(o.w);
    ((ushort4*)(ob + (size_t)t * D_))[tid] = h;
  }
}

// --------------------------- fp32 tiled GEMM: C = A*B (+resid) -------------
// A: MxK row-major (lda), B: KxN row-major (ldb), C: MxN (ldc).
// 128x128 block tile, BK=16, 256 threads, 8x8 per thread.
template<bool RESID>
__global__ __launch_bounds__(256) void gemm_f32(const float* __restrict__ A,
                                                const float* __restrict__ Bm,
                                                const float* __restrict__ resid,
                                                float* __restrict__ C,
                                                int M, int N, int K,
                                                int lda, int ldb, int ldc) {
  __shared__ float As[16][132];   // transposed: As[k][m]
  __shared__ float Bs[16][132];   // Bs[k][n]
  const int tid = threadIdx.x;
  const int bm = blockIdx.y, bn = blockIdx.x;
  const int tr = tid >> 4, tc = tid & 15;
  const int sar = tid >> 1, sak = (tid & 1) * 8;
  const int sbk = tid >> 5, sbn = (tid & 31) * 4;
  const float* Ap = A + (size_t)(bm * 128 + sar) * lda + sak;
  const float* Bp = Bm + (size_t)sbk * ldb + bn * 128 + sbn;
  float acc[8][8];
  #pragma unroll
  for (int i = 0; i < 8; ++i)
    #pragma unroll
    for (int j = 0; j < 8; ++j) acc[i][j] = 0.0f;

  for (int kt = 0; kt < K; kt += 16) {
    __syncthreads();
    const float4 av0 = *(const float4*)(Ap + kt);
    const float4 av1 = *(const float4*)(Ap + kt + 4);
    const float4 bv0 = *(const float4*)(Bp + (size_t)kt * ldb);
    const float4 bv1 = *(const float4*)(Bp + (size_t)(kt + 8) * ldb);
    As[sak + 0][sar] = av0.x; As[sak + 1][sar] = av0.y;
    As[sak + 2][sar] = av0.z; As[sak + 3][sar] = av0.w;
    As[sak + 4][sar] = av1.x; As[sak + 5][sar] = av1.y;
    As[sak + 6][sar] = av1.z; As[sak + 7][sar] = av1.w;
    *(float4*)&Bs[sbk][sbn]     = bv0;
    *(float4*)&Bs[sbk + 8][sbn] = bv1;
    __syncthreads();
    #pragma unroll
    for (int k = 0; k < 16; ++k) {
      const float4 a0 = *(const float4*)&As[k][tr * 8];
      const float4 a1 = *(const float4*)&As[k][tr * 8 + 4];
      const float4 b0 = *(const float4*)&Bs[k][tc * 8];
      const float4 b1 = *(const float4*)&Bs[k][tc * 8 + 4];
      float a8[8], b8[8];
      a8[0]=a0.x; a8[1]=a0.y; a8[2]=a0.z; a8[3]=a0.w;
      a8[4]=a1.x; a8[5]=a1.y; a8[6]=a1.z; a8[7]=a1.w;
      b8[0]=b0.x; b8[1]=b0.y; b8[2]=b0.z; b8[3]=b0.w;
      b8[4]=b1.x; b8[5]=b1.y; b8[6]=b1.z; b8[7]=b1.w;
      #pragma unroll
      for (int i = 0; i < 8; ++i)
        #pragma unroll
        for (int j = 0; j < 8; ++j)
          acc[i][j] = fmaf(a8[i], b8[j], acc[i][j]);
    }
  }
  #pragma unroll
  for (int i = 0; i < 8; ++i) {
    const int row = bm * 128 + tr * 8 + i;
    float* cp = C + (size_t)row * ldc + bn * 128 + tc * 8;
    float4 v0 = make_float4(acc[i][0], acc[i][1], acc[i][2], acc[i][3]);
    float4 v1 = make_float4(acc[i][4], acc[i][5], acc[i][6], acc[i][7]);
    if (RESID) {
      const float* rp = resid + (size_t)row * ldc + bn * 128 + tc * 8;
      const float4 r0 = *(const float4*)rp;
      const float4 r1 = *(const float4*)(rp + 4);
      v0.x += r0.x; v0.y += r0.y; v0.z += r0.z; v0.w += r0.w;
      v1.x += r1.x; v1.y += r1.y; v1.z += r1.z; v1.w += r1.w;
    }
    *(float4*)cp       = v0;
    *(float4*)(cp + 4) = v1;
  }
}

// --------------------------- RoPE in-place on qkv fp32 ---------------------
__global__ __launch_bounds__(256) void rope_k(float* __restrict__ qkv) {
  const int i = blockIdx.x * 256 + threadIdx.x;   // over T_*H_*32
  const int j = i & 31;
  const int h = (i >> 5) & 15;
  const int t = i >> 9;
  const int s = t & (S_ - 1);
  // theta in fp64 then rounded: 1-ulp theta error is amplified by s<=2047.
  const float theta = (float)pow(10000.0, -(double)j / 32.0);
  const float fr = (float)s * theta;
  const float c = cosf(fr), sn = sinf(fr);
  float* qp = qkv + (size_t)t * 3072 + h * 64 + 2 * j;
  float* kp = qp + 1024;
  const float2 q = *(const float2*)qp;
  const float2 k = *(const float2*)kp;
  float2 qo, ko;
  qo.x = q.x * c - q.y * sn;  qo.y = q.x * sn + q.y * c;
  ko.x = k.x * c - k.y * sn;  ko.y = k.x * sn + k.y * c;
  *(float2*)qp = qo;
  *(float2*)kp = ko;
}

// --------------------------- fp32 flash attention --------------------------
// One block per (64-query tile, b*H+h). Online softmax. P overwrites Ks tile
// (Ks is dead after the score phase) to keep static LDS < 64 KB.
__global__ __launch_bounds__(256) void attn_k(const float* __restrict__ qkv,
                                              float* __restrict__ attnout) {
  __shared__ float Qs[64][68];
  __shared__ float Ks[64][68];   // reused as P after scores are computed
  __shared__ float Vs[64][68];
  __shared__ float red[64][17];
  __shared__ float rowM[64], rowL[64], alphaS[64];
  const int tid = threadIdx.x;
  const int qt = blockIdx.x, bh = blockIdx.y;
  const int b = bh >> 4, h = bh & 15;
  const float* base = qkv + (size_t)b * S_ * 3072 + h * 64;
  const int sc = tid & 63, sr = tid >> 6;
  #pragma unroll
  for (int i = 0; i < 16; ++i) {
    const int r = i * 4 + sr;
    Qs[r][sc] = base[(size_t)(qt * 64 + r) * 3072 + sc];
  }
  if (tid < 64) { rowM[tid] = -__builtin_inff(); rowL[tid] = 0.0f; }
  const int r0 = (tid >> 4) * 4, c0 = (tid & 15) * 4, tc16 = tid & 15;
  float O[4][4];
  #pragma unroll
  for (int i = 0; i < 4; ++i)
    #pragma unroll
    for (int j = 0; j < 4; ++j) O[i][j] = 0.0f;

  for (int kt = 0; kt <= qt; ++kt) {
    __syncthreads();
    #pragma unroll
    for (int i = 0; i < 16; ++i) {
      const int r = i * 4 + sr;
      const size_t gg = (size_t)(kt * 64 + r) * 3072;
      Ks[r][sc] = base[gg + 1024 + sc];
      Vs[r][sc] = base[gg + 2048 + sc];
    }
    __syncthreads();
    // scores: S = Q K^T
    float s[4][4];
    #pragma unroll
    for (int i = 0; i < 4; ++i)
      #pragma unroll
      for (int j = 0; j < 4; ++j) s[i][j] = 0.0f;
    #pragma unroll
    for (int k4 = 0; k4 < 16; ++k4) {
      float4 qv[4], kv[4];
      #pragma unroll
      for (int i = 0; i < 4; ++i) qv[i] = *(const float4*)&Qs[r0 + i][k4 * 4];
      #pragma unroll
      for (int j = 0; j < 4; ++j) kv[j] = *(const float4*)&Ks[c0 + j][k4 * 4];
      #pragma unroll
      for (int i = 0; i < 4; ++i)
        #pragma unroll
        for (int j = 0; j < 4; ++j)
          s[i][j] += qv[i].x*kv[j].x + qv[i].y*kv[j].y + qv[i].z*kv[j].z + qv[i].w*kv[j].w;
    }
    const bool diag = (kt == qt);
    #pragma unroll
    for (int i = 0; i < 4; ++i) {
      float pm = -__builtin_inff();
      #pragma unroll
      for (int j = 0; j < 4; ++j) {
        if (diag && (c0 + j > r0 + i)) s[i][j] = -__builtin_inff();
        else                           s[i][j] *= 0.125f;
        pm = fmaxf(pm, s[i][j]);
      }
      red[r0 + i][tc16] = pm;
    }
    __syncthreads();
    if (tid < 64) {
      float mx = rowM[tid];
      #pragma unroll
      for (int c = 0; c < 16; ++c) mx = fmaxf(mx, red[tid][c]);
      alphaS[tid] = expf(rowM[tid] - mx);   // first tile: exp(-inf)=0
      rowM[tid] = mx;
    }
    __syncthreads();
    // P = exp(S - m); written into Ks storage (dead now). O rescale by alpha.
    #pragma unroll
    for (int i = 0; i < 4; ++i) {
      const float al = alphaS[r0 + i];
      const float mr = rowM[r0 + i];
      #pragma unroll
      for (int j = 0; j < 4; ++j) O[i][j] *= al;
      float4 pv;
      float psum = 0.0f;
      pv.x = (s[i][0] > -__builtin_inff()) ? expf(s[i][0] - mr) : 0.0f; psum += pv.x;
      pv.y = (s[i][1] > -__builtin_inff()) ? expf(s[i][1] - mr) : 0.0f; psum += pv.y;
      pv.z = (s[i][2] > -__builtin_inff()) ? expf(s[i][2] - mr) : 0.0f; psum += pv.z;
      pv.w = (s[i][3] > -__builtin_inff()) ? expf(s[i][3] - mr) : 0.0f; psum += pv.w;
      *(float4*)&Ks[r0 + i][c0] = pv;
      red[r0 + i][tc16] = psum;
    }
    __syncthreads();
    if (tid < 64) {
      float sm = 0.0f;
      #pragma unroll
      for (int c = 0; c < 16; ++c) sm += red[tid][c];
      rowL[tid] = rowL[tid] * alphaS[tid] + sm;
    }
    // O += P V   (P lives in Ks)
    #pragma unroll
    for (int k4 = 0; k4 < 16; ++k4) {
      const float4 vv0 = *(const float4*)&Vs[k4 * 4 + 0][c0];
      const float4 vv1 = *(const float4*)&Vs[k4 * 4 + 1][c0];
      const float4 vv2 = *(const float4*)&Vs[k4 * 4 + 2][c0];
      const float4 vv3 = *(const float4*)&Vs[k4 * 4 + 3][c0];
      #pragma unroll
      for (int i = 0; i < 4; ++i) {
        const float4 p = *(const float4*)&Ks[r0 + i][k4 * 4];
        O[i][0] += p.x*vv0.x + p.y*vv1.x + p.z*vv2.x + p.w*vv3.x;
        O[i][1] += p.x*vv0.y + p.y*vv1.y + p.z*vv2.y + p.w*vv3.y;
        O[i][2] += p.x*vv0.z + p.y*vv1.z + p.z*vv2.z + p.w*vv3.z;
        O[i][3] += p.x*vv0.w + p.y*vv1.w + p.z*vv2.w + p.w*vv3.w;
      }
    }
  }
  __syncthreads();
  #pragma unroll
  for (int i = 0; i < 4; ++i) {
    const float inv = 1.0f / rowL[r0 + i];
    float4 o = make_float4(O[i][0]*inv, O[i][1]*inv, O[i][2]*inv, O[i][3]*inv);
    *(float4*)&attnout[(size_t)(b * S_ + qt * 64 + r0 + i) * D_ + h * 64 + c0] = o;
  }
}

// --------------------------- router: logits + top2 + capacity assign -------
__global__ __launch_bounds__(256) void router_k(const float* __restrict__ y2,
                                                const float* __restrict__ wr,
                                                int*   __restrict__ cnt,
                                                int*   __restrict__ tok_e,
                                                float* __restrict__ tok_g,
                                                int*   __restrict__ tok_p,
                                                int*   __restrict__ etok) {
  const int wave = threadIdx.x >> 6, lane = threadIdx.x & 63;
  const int t = blockIdx.x * 4 + wave;
  const float* xr = y2 + (size_t)t * D_;
  float acc[8];
  #pragma unroll
  for (int e = 0; e < 8; ++e) acc[e] = 0.0f;
  for (int c = 0; c < 16; ++c) {
    const float xv = xr[c * 64 + lane];
    const float* w = wr + (size_t)(c * 64 + lane) * 8;
    #pragma unroll
    for (int e = 0; e < 8; ++e) acc[e] = fmaf(xv, w[e], acc[e]);
  }
  #pragma unroll
  for (int off = 32; off; off >>= 1)
    #pragma unroll
    for (int e = 0; e < 8; ++e) acc[e] += __shfl_down(acc[e], off);
  if (lane == 0) {
    float mx = acc[0];
    #pragma unroll
    for (int e = 1; e < 8; ++e) mx = fmaxf(mx, acc[e]);
    float ex[8], sum = 0.0f;
    #pragma unroll
    for (int e = 0; e < 8; ++e) { ex[e] = expf(acc[e] - mx); sum += ex[e]; }
    int e1 = 0;
    #pragma unroll
    for (int e = 1; e < 8; ++e) if (acc[e] > acc[e1]) e1 = e;   // stable argmax
    int e2 = (e1 == 0) ? 1 : 0;
    #pragma unroll
    for (int e = 0; e < 8; ++e) if (e != e1 && acc[e] > acc[e2]) e2 = e;
    const float g1v = ex[e1] / sum, g2v = ex[e2] / sum;
    int p1 = atomicAdd(&cnt[e1], 1);
    int p2 = atomicAdd(&cnt[e2], 1);
    if (p1 < CAP_) etok[e1 * CAP_ + p1] = t; else p1 = -1;
    if (p2 < CAP_) etok[e2 * CAP_ + p2] = t; else p2 = -1;
    tok_e[2*t] = e1;   tok_e[2*t+1] = e2;
    tok_g[2*t] = g1v;  tok_g[2*t+1] = g2v;
    tok_p[2*t] = p1;   tok_p[2*t+1] = p2;
  }
}

// --------------------------- gather tokens per expert (bf16) ---------------
__global__ __launch_bounds__(256) void gather_k(const u16* __restrict__ y2b,
                                                const int* __restrict__ etok,
                                                const int* __restrict__ cnt,
                                                u16* __restrict__ xe) {
  const int e = blockIdx.y, pos = blockIdx.x, tid = threadIdx.x;
  const int n = min(cnt[e], CAP_);
  ushort4* dst = (ushort4*)(xe + (size_t)(e * CAP_ + pos) * D_) + tid;
  if (pos < n) {
    const int t = etok[e * CAP_ + pos];
    *dst = ((const ushort4*)(y2b + (size_t)t * D_))[tid];
  } else {
    *dst = make_ushort4(0, 0, 0, 0);
  }
}

// --------------------------- bf16 MFMA GEMM: C = A * Bt^T ------------------
// A: MxK bf16 row-major (lda). Bt: NxK bf16 row-major (ldb) i.e. B transposed.
// 128x128 tile, BK=32, 4 waves in 2x2, mfma_f32_16x16x32_bf16.
template<typename OT, bool RELU>
__global__ __launch_bounds__(256) void gemm_bt(const u16* __restrict__ A,
                                               const u16* __restrict__ Bt,
                                               OT* __restrict__ C,
                                               int M, int N, int K,
                                               int lda, int ldb, int ldc,
                                               long sAz, long sBz, long sCz) {
  __shared__ u16 As[128 * 32];
  __shared__ u16 Bs[128 * 32];
  const int tid = threadIdx.x;
  A  += (size_t)blockIdx.z * sAz;
  Bt += (size_t)blockIdx.z * sBz;
  C  += (size_t)blockIdx.z * sCz;
  const int bm = blockIdx.y, bn = blockIdx.x;
  const int lane = tid & 63, wave = tid >> 6;
  const int wy = wave >> 1, wx = wave & 1;
  const int l15 = lane & 15, lq = lane >> 4;
  const int ar = tid >> 1, ac = (tid & 1) * 16;
  f32x4 acc[4][4];
  #pragma unroll
  for (int i = 0; i < 4; ++i)
    #pragma unroll
    for (int j = 0; j < 4; ++j)
      #pragma unroll
      for (int r = 0; r < 4; ++r) acc[i][j][r] = 0.0f;
  const u16* Ag = A  + (size_t)(bm * 128 + ar) * lda + ac;
  const u16* Bg = Bt + (size_t)(bn * 128 + ar) * ldb + ac;

  for (int kt = 0; kt < K; kt += 32) {
    __syncthreads();
    *(ushort8v*)&As[ar * 32 + ac]     = *(const ushort8v*)(Ag + kt);
    *(ushort8v*)&As[ar * 32 + ac + 8] = *(const ushort8v*)(Ag + kt + 8);
    *(ushort8v*)&Bs[ar * 32 + ac]     = *(const ushort8v*)(Bg + kt);
    *(ushort8v*)&Bs[ar * 32 + ac + 8] = *(const ushort8v*)(Bg + kt + 8);
    __syncthreads();
    short8 a[4], b[4];
    #pragma unroll
    for (int i = 0; i < 4; ++i)
      a[i] = *(const short8*)&As[(wy * 64 + i * 16 + l15) * 32 + lq * 8];
    #pragma unroll
    for (int j = 0; j < 4; ++j)
      b[j] = *(const short8*)&Bs[(wx * 64 + j * 16 + l15) * 32 + lq * 8];
    #pragma unroll
    for (int i = 0; i < 4; ++i)
      #pragma unroll
      for (int j = 0; j < 4; ++j)
        acc[i][j] = __builtin_amdgcn_mfma_f32_16x16x32_bf16(a[i], b[j], acc[i][j], 0, 0, 0);
  }
  #pragma unroll
  for (int i = 0; i < 4; ++i)
    #pragma unroll
    for (int j = 0; j < 4; ++j)
      #pragma unroll
      for (int r = 0; r < 4; ++r) {
        const int row = bm * 128 + wy * 64 + i * 16 + lq * 4 + r;
        const int col = bn * 128 + wx * 64 + j * 16 + l15;
        float v = acc[i][j][r];
        if (RELU) v = fmaxf(v, 0.0f);
        cstore(C + (size_t)row * ldc + col, v);
      }
}

// --------------------------- weight transpose fp32 -> bf16^T ---------------
// src [z][R][C] fp32 -> dst [z][C][R] bf16
__global__ __launch_bounds__(256) void transpose_bf_k(const float* __restrict__ src,
                                                      u16* __restrict__ dst,
                                                      int R, int C) {
  __shared__ float tile[32][33];
  const int tid = threadIdx.x;
  const size_t zoff = (size_t)blockIdx.z * R * C;
  const int r0 = blockIdx.y * 32, c0 = blockIdx.x * 32;
  const int tx = tid & 31, ty = tid >> 5;
  #pragma unroll
  for (int i = 0; i < 4; ++i)
    tile[ty + i * 8][tx] = src[zoff + (size_t)(r0 + ty + i * 8) * C + c0 + tx];
  __syncthreads();
  #pragma unroll
  for (int i = 0; i < 4; ++i)
    dst[zoff + (size_t)(c0 + ty + i * 8) * R + r0 + tx] = f2bf(tile[tx][ty + i * 8]);
}

// --------------------------- final combine ---------------------------------
__global__ __launch_bounds__(256) void combine_k(const float* __restrict__ x2,
                                                 const float* __restrict__ ye,
                                                 const int*   __restrict__ tok_e,
                                                 const float* __restrict__ tok_g,
                                                 const int*   __restrict__ tok_p,
                                                 float* __restrict__ out) {
  const int t = blockIdx.x, tid = threadIdx.x;
  float4 v = ((const float4*)(x2 + (size_t)t * D_))[tid];
  #pragma unroll
  for (int r = 0; r < 2; ++r) {
    const int p = tok_p[2 * t + r];
    if (p >= 0) {
      const int e = tok_e[2 * t + r];
      const float g = tok_g[2 * t + r];
      const float4 y = ((const float4*)(ye + (size_t)(e * CAP_ + p) * D_))[tid];
      v.x = fmaf(g, y.x, v.x);
      v.y = fmaf(g, y.y, v.y);
      v.z = fmaf(g, y.z, v.z);
      v.w = fmaf(g, y.w, v.w);
    }
  }
  ((float4*)(out + (size_t)t * D_))[tid] = v;
}

// ---------------------------------------------------------------------------
extern "C" void kernel_launch(void* const* d_in, const int* in_sizes, int n_in,
                              void* d_out, int out_size, void* d_ws, size_t ws_size,
                              hipStream_t stream) {
  const float* x    = (const float*)d_in[0];
  const float* g1   = (const float*)d_in[1];
  const float* wqkv = (const float*)d_in[2];
  const float* wo   = (const float*)d_in[3];
  const float* g2   = (const float*)d_in[4];
  const float* wr   = (const float*)d_in[5];
  const float* w1   = (const float*)d_in[6];
  const float* w2   = (const float*)d_in[7];
  float* out = (float*)d_out;
  char* ws = (char*)d_ws;
  const size_t MB = 1ull << 20;

  // Phase-aliased workspace layout (~233 MB):
  float* y1    = (float*)(ws + 0);          // 16MB, dead after QKV GEMM
  float* attnf = (float*)(ws + 16 * MB);    // 16MB, dead after out-proj
  u16*   hbf   = (u16*)  (ws + 0);          // 40MB, MoE hidden (aliases y1+attnf)
  float* qkv   = (float*)(ws + 40 * MB);    // 48MB, dead after attention
  u16*   xe    = (u16*)  (ws + 40 * MB);    // 20MB, aliases qkv
  float* x2    = (float*)(ws + 88 * MB);    // 16MB
  float* y2    = (float*)(ws + 104 * MB);   // 16MB (fp32 for router!)
  u16*   y2b   = (u16*)  (ws + 120 * MB);   // 8MB
  u16*   w1t   = (u16*)  (ws + 128 * MB);   // 32MB  [E][FFN][D] bf16
  u16*   w2t   = (u16*)  (ws + 160 * MB);   // 32MB  [E][D][FFN] bf16
  float* ye    = (float*)(ws + 192 * MB);   // 40MB
  int*   cnt   = (int*)  (ws + 232 * MB);
  int*   tok_e = cnt + 16;                  // 2*T
  float* tok_g = (float*)(tok_e + 2 * T_);  // 2*T
  int*   tok_p = (int*)  (tok_g + 2 * T_);  // 2*T
  int*   etok  = tok_p + 2 * T_;            // E*CAP

  init_k<<<1, 64, 0, stream>>>(cnt);
  transpose_bf_k<<<dim3(FFN_/32, D_/32, E_), 256, 0, stream>>>(w1, w1t, D_, FFN_);
  transpose_bf_k<<<dim3(D_/32, FFN_/32, E_), 256, 0, stream>>>(w2, w2t, FFN_, D_);

  // x -> rmsnorm -> y1 (fp32)
  rmsnorm_k<<<T_, 256, 0, stream>>>(x, g1, y1, (u16*)nullptr);
  // y1 @ w_qkv -> qkv (fp32)
  gemm_f32<false><<<dim3(3 * D_ / 128, T_ / 128), 256, 0, stream>>>(
      y1, wqkv, nullptr, qkv, T_, 3 * D_, D_, D_, 3 * D_, 3 * D_);
  // RoPE in-place on q,k
  rope_k<<<T_ * H_ * 32 / 256, 256, 0, stream>>>(qkv);
  // flash attention (fp32) -> attnf [B,S,D]
  attn_k<<<dim3(S_ / 64, B_ * H_), 256, 0, stream>>>(qkv, attnf);
  // attnf @ w_o + x -> x2
  gemm_f32<true><<<dim3(D_ / 128, T_ / 128), 256, 0, stream>>>(
      attnf, wo, x, x2, T_, D_, D_, D_, D_, D_);
  // x2 -> rmsnorm -> y2 (fp32) + y2b (bf16)
  rmsnorm_k<<<T_, 256, 0, stream>>>(x2, g2, y2, y2b);
  // router (fp32 logits, top-2, capacity assignment)
  router_k<<<T_ / 4, 256, 0, stream>>>(y2, wr, cnt, tok_e, tok_g, tok_p, etok);
  // gather per-expert token rows (bf16)
  gather_k<<<dim3(CAP_, E_), 256, 0, stream>>>(y2b, etok, cnt, xe);
  // h = relu(xe @ w1) (bf16 out), batched over experts
  gemm_bt<u16, true><<<dim3(FFN_/128, CAP_/128, E_), 256, 0, stream>>>(
      xe, w1t, hbf, CAP_, FFN_, D_, D_, D_, FFN_,
      (long)CAP_ * D_, (long)FFN_ * D_, (long)CAP_ * FFN_);
  // ye = h @ w2 (fp32 out)
  gemm_bt<float, false><<<dim3(D_/128, CAP_/128, E_), 256, 0, stream>>>(
      hbf, w2t, ye, CAP_, D_, FFN_, FFN_, FFN_, D_,
      (long)CAP_ * FFN_, (long)D_ * FFN_, (long)CAP_ * D_);
  // out = x2 + sum_r gate_r * ye[...]
  combine_k<<<T_, 256, 0, stream>>>(x2, ye, tok_e, tok_g, tok_p, out);
}

// Round 2
// 1183.424 us; speedup vs baseline: 2.0572x; 2.0572x over previous
//
#include <hip/hip_runtime.h>
#include <math.h>

// ---------------------------------------------------------------------------
// Fused transformer block on MI355X.
// Precision strategy: everything feeding the MoE router must match fp32
// closely (min top-2 logit gap ~3e-5 over 4096 tokens). Attention now uses
// split-bf16 MFMA: x = hi + lo (two bf16), products hh+hl+lh -> ~2^-17 rel
// error, ~1e-6 at the logits -> routing preserved. Post-routing MoE GEMMs use
// plain bf16 MFMA.
// ---------------------------------------------------------------------------

#define B_   2
#define S_   2048
#define D_   1024
#define H_   16
#define HD_  64
#define FFN_ 2048
#define E_   8
#define CAP_ 1280
#define T_   (B_*S_)

typedef unsigned short u16;
typedef __attribute__((ext_vector_type(8))) short     short8;    // MFMA bf16x8 operand
typedef __attribute__((ext_vector_type(8))) unsigned short ushort8v;
typedef __attribute__((ext_vector_type(4))) float     f32x4;

__device__ __forceinline__ u16 f2bf(float f) {
  unsigned u = __float_as_uint(f);
  return (u16)((u + 0x7fffu + ((u >> 16) & 1u)) >> 16);   // RNE
}
__device__ __forceinline__ float bf2f(u16 h) {
  return __uint_as_float(((unsigned)h) << 16);
}

__device__ __forceinline__ void cstore(float* p, float v) { *p = v; }
__device__ __forceinline__ void cstore(u16* p, float v)   { *p = f2bf(v); }

// --------------------------- init: zero expert counters --------------------
__global__ void init_k(int* cnt) {
  if (threadIdx.x < 16) cnt[threadIdx.x] = 0;
}

// --------------------------- RMSNorm (fp32 in, fp32 + optional bf16 out) ---
__global__ __launch_bounds__(256) void rmsnorm_k(const float* __restrict__ x,
                                                 const float* __restrict__ g,
                                                 float* __restrict__ of,
                                                 u16*   __restrict__ ob) {
  const int t = blockIdx.x, tid = threadIdx.x;
  const float4 xv = ((const float4*)(x + (size_t)t * D_))[tid];
  float ss = xv.x*xv.x + xv.y*xv.y + xv.z*xv.z + xv.w*xv.w;
  #pragma unroll
  for (int off = 32; off; off >>= 1) ss += __shfl_down(ss, off);
  __shared__ float wsum[4];
  if ((tid & 63) == 0) wsum[tid >> 6] = ss;
  __syncthreads();
  const float tot = wsum[0] + wsum[1] + wsum[2] + wsum[3];
  const float rms = 1.0f / sqrtf(tot * (1.0f / D_) + 1e-6f);
  const float4 gv = ((const float4*)g)[tid];
  float4 o;
  o.x = gv.x * xv.x * rms;
  o.y = gv.y * xv.y * rms;
  o.z = gv.z * xv.z * rms;
  o.w = gv.w * xv.w * rms;
  if (of) ((float4*)(of + (size_t)t * D_))[tid] = o;
  if (ob) {
    ushort4 h;
    h.x = f2bf(o.x); h.y = f2bf(o.y); h.z = f2bf(o.z); h.w = f2bf(o.w);
    ((ushort4*)(ob + (size_t)t * D_))[tid] = h;
  }
}

// --------------------------- fp32 tiled GEMM: C = A*B (+resid) -------------
template<bool RESID>
__global__ __launch_bounds__(256) void gemm_f32(const float* __restrict__ A,
                                                const float* __restrict__ Bm,
                                                const float* __restrict__ resid,
                                                float* __restrict__ C,
                                                int M, int N, int K,
                                                int lda, int ldb, int ldc) {
  __shared__ float As[16][132];   // transposed: As[k][m]
  __shared__ float Bs[16][132];   // Bs[k][n]
  const int tid = threadIdx.x;
  const int bm = blockIdx.y, bn = blockIdx.x;
  const int tr = tid >> 4, tc = tid & 15;
  const int sar = tid >> 1, sak = (tid & 1) * 8;
  const int sbk = tid >> 5, sbn = (tid & 31) * 4;
  const float* Ap = A + (size_t)(bm * 128 + sar) * lda + sak;
  const float* Bp = Bm + (size_t)sbk * ldb + bn * 128 + sbn;
  float acc[8][8];
  #pragma unroll
  for (int i = 0; i < 8; ++i)
    #pragma unroll
    for (int j = 0; j < 8; ++j) acc[i][j] = 0.0f;

  for (int kt = 0; kt < K; kt += 16) {
    __syncthreads();
    const float4 av0 = *(const float4*)(Ap + kt);
    const float4 av1 = *(const float4*)(Ap + kt + 4);
    const float4 bv0 = *(const float4*)(Bp + (size_t)kt * ldb);
    const float4 bv1 = *(const float4*)(Bp + (size_t)(kt + 8) * ldb);
    As[sak + 0][sar] = av0.x; As[sak + 1][sar] = av0.y;
    As[sak + 2][sar] = av0.z; As[sak + 3][sar] = av0.w;
    As[sak + 4][sar] = av1.x; As[sak + 5][sar] = av1.y;
    As[sak + 6][sar] = av1.z; As[sak + 7][sar] = av1.w;
    *(float4*)&Bs[sbk][sbn]     = bv0;
    *(float4*)&Bs[sbk + 8][sbn] = bv1;
    __syncthreads();
    #pragma unroll
    for (int k = 0; k < 16; ++k) {
      const float4 a0 = *(const float4*)&As[k][tr * 8];
      const float4 a1 = *(const float4*)&As[k][tr * 8 + 4];
      const float4 b0 = *(const float4*)&Bs[k][tc * 8];
      const float4 b1 = *(const float4*)&Bs[k][tc * 8 + 4];
      float a8[8], b8[8];
      a8[0]=a0.x; a8[1]=a0.y; a8[2]=a0.z; a8[3]=a0.w;
      a8[4]=a1.x; a8[5]=a1.y; a8[6]=a1.z; a8[7]=a1.w;
      b8[0]=b0.x; b8[1]=b0.y; b8[2]=b0.z; b8[3]=b0.w;
      b8[4]=b1.x; b8[5]=b1.y; b8[6]=b1.z; b8[7]=b1.w;
      #pragma unroll
      for (int i = 0; i < 8; ++i)
        #pragma unroll
        for (int j = 0; j < 8; ++j)
          acc[i][j] = fmaf(a8[i], b8[j], acc[i][j]);
    }
  }
  #pragma unroll
  for (int i = 0; i < 8; ++i) {
    const int row = bm * 128 + tr * 8 + i;
    float* cp = C + (size_t)row * ldc + bn * 128 + tc * 8;
    float4 v0 = make_float4(acc[i][0], acc[i][1], acc[i][2], acc[i][3]);
    float4 v1 = make_float4(acc[i][4], acc[i][5], acc[i][6], acc[i][7]);
    if (RESID) {
      const float* rp = resid + (size_t)row * ldc + bn * 128 + tc * 8;
      const float4 r0 = *(const float4*)rp;
      const float4 r1 = *(const float4*)(rp + 4);
      v0.x += r0.x; v0.y += r0.y; v0.z += r0.z; v0.w += r0.w;
      v1.x += r1.x; v1.y += r1.y; v1.z += r1.z; v1.w += r1.w;
    }
    *(float4*)cp       = v0;
    *(float4*)(cp + 4) = v1;
  }
}

// --------------------------- RoPE + split q,k -> bf16 hi/lo ----------------
// Writes q (pre-scaled by 1/8) and k, RoPE'd, as hi/lo bf16 in [bh][s][d].
__global__ __launch_bounds__(256) void ropesplit_k(const float* __restrict__ qkv,
                                                   u16* __restrict__ qhi, u16* __restrict__ qlo,
                                                   u16* __restrict__ khi, u16* __restrict__ klo) {
  const int i = blockIdx.x * 256 + threadIdx.x;   // over T_*H_*32
  const int j = i & 31;
  const int h = (i >> 5) & 15;
  const int t = i >> 9;
  const int s = t & (S_ - 1);
  const int b = t >> 11;
  const int bh = b * 16 + h;
  const float theta = (float)pow(10000.0, -(double)j / 32.0);
  const float fr = (float)s * theta;
  const float c = cosf(fr), sn = sinf(fr);
  const float2 q = *(const float2*)(qkv + (size_t)t * 3072 + h * 64 + 2 * j);
  const float2 k = *(const float2*)(qkv + (size_t)t * 3072 + 1024 + h * 64 + 2 * j);
  const float q0 = (q.x * c - q.y * sn) * 0.125f;
  const float q1 = (q.x * sn + q.y * c) * 0.125f;
  const float k0 = k.x * c - k.y * sn;
  const float k1 = k.x * sn + k.y * c;
  const size_t o = ((size_t)bh * S_ + s) * 32 + j;   // uint (2xu16) index
  const u16 qh0 = f2bf(q0), qh1 = f2bf(q1);
  const u16 kh0 = f2bf(k0), kh1 = f2bf(k1);
  ((unsigned*)qhi)[o] = (unsigned)qh0 | ((unsigned)qh1 << 16);
  ((unsigned*)khi)[o] = (unsigned)kh0 | ((unsigned)kh1 << 16);
  const u16 ql0 = f2bf(q0 - bf2f(qh0)), ql1 = f2bf(q1 - bf2f(qh1));
  const u16 kl0 = f2bf(k0 - bf2f(kh0)), kl1 = f2bf(k1 - bf2f(kh1));
  ((unsigned*)qlo)[o] = (unsigned)ql0 | ((unsigned)ql1 << 16);
  ((unsigned*)klo)[o] = (unsigned)kl0 | ((unsigned)kl1 << 16);
}

// --------------------------- V: transpose + split -> [bh][d][s] bf16 -------
__global__ __launch_bounds__(256) void vsplit_k(const float* __restrict__ qkv,
                                                u16* __restrict__ vthi,
                                                u16* __restrict__ vtlo) {
  __shared__ float tile[64][65];
  const int st = blockIdx.x, bh = blockIdx.y;
  const int b = bh >> 4, h = bh & 15;
  const int tid = threadIdx.x;
  const int c = tid & 63, r4 = tid >> 6;
  #pragma unroll
  for (int i = 0; i < 16; ++i) {
    const int r = i * 4 + r4;
    tile[r][c] = qkv[(size_t)(b * S_ + st * 64 + r) * 3072 + 2048 + h * 64 + c];
  }
  __syncthreads();
  #pragma unroll
  for (int i = 0; i < 16; ++i) {
    const int d = i * 4 + r4;
    const float v = tile[c][d];
    const u16 hi = f2bf(v);
    const size_t o = ((size_t)bh * 64 + d) * S_ + st * 64 + c;
    vthi[o] = hi;
    vtlo[o] = f2bf(v - bf2f(hi));
  }
}

// --------------------------- split-bf16 MFMA flash attention ---------------
// Block: 64-query tile x one (b,h). 4 waves, 16 query rows each.
// S = (Qh+Ql)(Kh+Kl)^T and O += (Ph+Pl)(Vh+Vl) via 3-product splits.
// LDS rows padded to 68 u16 (stride 136B -> 2-way bank aliasing = free).
__global__ __launch_bounds__(256) void attn_mfma_k(const u16* __restrict__ qhi,
                                                   const u16* __restrict__ qlo,
                                                   const u16* __restrict__ khi,
                                                   const u16* __restrict__ klo,
                                                   const u16* __restrict__ vthi,
                                                   const u16* __restrict__ vtlo,
                                                   float* __restrict__ attnout) {
  __shared__ u16 Kh[64 * 68], Kl[64 * 68];   // [key][dim]
  __shared__ u16 Vh[64 * 68], Vl[64 * 68];   // [dim][key]
  __shared__ u16 Ph[4][16 * 68], Pl[4][16 * 68];  // per-wave P round-trip
  const int tid = threadIdx.x, lane = tid & 63, wave = tid >> 6;
  const int qt = gridDim.x - 1 - blockIdx.x;   // longest blocks dispatch first
  const int bh = blockIdx.y;
  const int l15 = lane & 15, lq = lane >> 4;
  const size_t hb = (size_t)bh * S_ * 64;
  const int qrow = qt * 64 + wave * 16 + l15;
  short8 qh[2], ql[2];
  qh[0] = *(const short8*)(qhi + hb + (size_t)qrow * 64 + lq * 8);
  qh[1] = *(const short8*)(qhi + hb + (size_t)qrow * 64 + 32 + lq * 8);
  ql[0] = *(const short8*)(qlo + hb + (size_t)qrow * 64 + lq * 8);
  ql[1] = *(const short8*)(qlo + hb + (size_t)qrow * 64 + 32 + lq * 8);
  f32x4 O[4];
  float m_i[4], l_i[4];
  #pragma unroll
  for (int n = 0; n < 4; ++n)
    #pragma unroll
    for (int r = 0; r < 4; ++r) O[n][r] = 0.0f;
  #pragma unroll
  for (int r = 0; r < 4; ++r) { m_i[r] = -__builtin_inff(); l_i[r] = 0.0f; }

  for (int kt = 0; kt <= qt; ++kt) {
    __syncthreads();
    #pragma unroll
    for (int it = 0; it < 2; ++it) {
      const int idx = it * 256 + tid;
      const int row = idx >> 3, c8 = (idx & 7) * 8;
      const size_t koff = hb + (size_t)(kt * 64 + row) * 64 + c8;
      *(ushort8v*)&Kh[row * 68 + c8] = *(const ushort8v*)(khi + koff);
      *(ushort8v*)&Kl[row * 68 + c8] = *(const ushort8v*)(klo + koff);
      const size_t voff = ((size_t)bh * 64 + row) * S_ + kt * 64 + c8;
      *(ushort8v*)&Vh[row * 68 + c8] = *(const ushort8v*)(vthi + voff);
      *(ushort8v*)&Vl[row * 68 + c8] = *(const ushort8v*)(vtlo + voff);
    }
    __syncthreads();
    // ---- S = Q K^T (3-product split) ----
    f32x4 sc[4];
    #pragma unroll
    for (int n = 0; n < 4; ++n)
      #pragma unroll
      for (int r = 0; r < 4; ++r) sc[n][r] = 0.0f;
    #pragma unroll
    for (int n = 0; n < 4; ++n) {
      const int krow = (n * 16 + l15) * 68 + lq * 8;
      const short8 kb0 = *(const short8*)&Kh[krow];
      const short8 kb1 = *(const short8*)&Kh[krow + 32];
      const short8 kl0 = *(const short8*)&Kl[krow];
      const short8 kl1 = *(const short8*)&Kl[krow + 32];
      sc[n] = __builtin_amdgcn_mfma_f32_16x16x32_bf16(qh[0], kb0, sc[n], 0, 0, 0);
      sc[n] = __builtin_amdgcn_mfma_f32_16x16x32_bf16(qh[1], kb1, sc[n], 0, 0, 0);
      sc[n] = __builtin_amdgcn_mfma_f32_16x16x32_bf16(qh[0], kl0, sc[n], 0, 0, 0);
      sc[n] = __builtin_amdgcn_mfma_f32_16x16x32_bf16(qh[1], kl1, sc[n], 0, 0, 0);
      sc[n] = __builtin_amdgcn_mfma_f32_16x16x32_bf16(ql[0], kb0, sc[n], 0, 0, 0);
      sc[n] = __builtin_amdgcn_mfma_f32_16x16x32_bf16(ql[1], kb1, sc[n], 0, 0, 0);
    }
    // ---- causal mask on the diagonal tile ----
    if (kt == qt) {
      #pragma unroll
      for (int n = 0; n < 4; ++n)
        #pragma unroll
        for (int r = 0; r < 4; ++r)
          if (n * 16 + l15 > wave * 16 + lq * 4 + r) sc[n][r] = -__builtin_inff();
    }
    // ---- online softmax (rows live across 16 lanes l15, per reg r) ----
    float al[4];
    #pragma unroll
    for (int r = 0; r < 4; ++r) {
      float mx = fmaxf(fmaxf(sc[0][r], sc[1][r]), fmaxf(sc[2][r], sc[3][r]));
      mx = fmaxf(mx, __shfl_xor(mx, 1));
      mx = fmaxf(mx, __shfl_xor(mx, 2));
      mx = fmaxf(mx, __shfl_xor(mx, 4));
      mx = fmaxf(mx, __shfl_xor(mx, 8));
      const float mn = fmaxf(m_i[r], mx);
      al[r] = __expf(m_i[r] - mn);
      m_i[r] = mn;
    }
    f32x4 p[4];
    #pragma unroll
    for (int n = 0; n < 4; ++n)
      #pragma unroll
      for (int r = 0; r < 4; ++r) p[n][r] = __expf(sc[n][r] - m_i[r]);
    #pragma unroll
    for (int r = 0; r < 4; ++r) {
      float rs = p[0][r] + p[1][r] + p[2][r] + p[3][r];
      rs += __shfl_xor(rs, 1);
      rs += __shfl_xor(rs, 2);
      rs += __shfl_xor(rs, 4);
      rs += __shfl_xor(rs, 8);
      l_i[r] = l_i[r] * al[r] + rs;
      O[0][r] *= al[r]; O[1][r] *= al[r]; O[2][r] *= al[r]; O[3][r] *= al[r];
    }
    // ---- P: C-layout regs -> LDS in A-layout, split hi/lo ----
    #pragma unroll
    for (int n = 0; n < 4; ++n)
      #pragma unroll
      for (int r = 0; r < 4; ++r) {
        const float v = p[n][r];
        const u16 hi = f2bf(v);
        const int a = (lq * 4 + r) * 68 + n * 16 + l15;
        Ph[wave][a] = hi;
        Pl[wave][a] = f2bf(v - bf2f(hi));
      }
    asm volatile("s_waitcnt lgkmcnt(0)" ::: "memory");
    short8 pah[2], pal[2];
    pah[0] = *(const short8*)&Ph[wave][l15 * 68 + lq * 8];
    pah[1] = *(const short8*)&Ph[wave][l15 * 68 + 32 + lq * 8];
    pal[0] = *(const short8*)&Pl[wave][l15 * 68 + lq * 8];
    pal[1] = *(const short8*)&Pl[wave][l15 * 68 + 32 + lq * 8];
    // ---- O += P V (3-product split); V in LDS is [dim][key] = B^T layout --
    #pragma unroll
    for (int n = 0; n < 4; ++n) {
      const int vrow = (n * 16 + l15) * 68 + lq * 8;
      const short8 vb0 = *(const short8*)&Vh[vrow];
      const short8 vb1 = *(const short8*)&Vh[vrow + 32];
      const short8 vl0 = *(const short8*)&Vl[vrow];
      const short8 vl1 = *(const short8*)&Vl[vrow + 32];
      O[n] = __builtin_amdgcn_mfma_f32_16x16x32_bf16(pah[0], vb0, O[n], 0, 0, 0);
      O[n] = __builtin_amdgcn_mfma_f32_16x16x32_bf16(pah[1], vb1, O[n], 0, 0, 0);
      O[n] = __builtin_amdgcn_mfma_f32_16x16x32_bf16(pah[0], vl0, O[n], 0, 0, 0);
      O[n] = __builtin_amdgcn_mfma_f32_16x16x32_bf16(pah[1], vl1, O[n], 0, 0, 0);
      O[n] = __builtin_amdgcn_mfma_f32_16x16x32_bf16(pal[0], vb0, O[n], 0, 0, 0);
      O[n] = __builtin_amdgcn_mfma_f32_16x16x32_bf16(pal[1], vb1, O[n], 0, 0, 0);
    }
  }
  const int b = bh >> 4, h = bh & 15;
  #pragma unroll
  for (int r = 0; r < 4; ++r) {
    const float inv = 1.0f / l_i[r];
    const int row = qt * 64 + wave * 16 + lq * 4 + r;
    float* op = attnout + (size_t)(b * S_ + row) * D_ + h * 64 + l15;
    #pragma unroll
    for (int n = 0; n < 4; ++n) op[n * 16] = O[n][r] * inv;
  }
}

// --------------------------- router: logits + top2 + capacity assign -------
__global__ __launch_bounds__(256) void router_k(const float* __restrict__ y2,
                                                const float* __restrict__ wr,
                                                int*   __restrict__ cnt,
                                                int*   __restrict__ tok_e,
                                                float* __restrict__ tok_g,
                                                int*   __restrict__ tok_p,
                                                int*   __restrict__ etok) {
  const int wave = threadIdx.x >> 6, lane = threadIdx.x & 63;
  const int t = blockIdx.x * 4 + wave;
  const float* xr = y2 + (size_t)t * D_;
  float acc[8];
  #pragma unroll
  for (int e = 0; e < 8; ++e) acc[e] = 0.0f;
  for (int c = 0; c < 16; ++c) {
    const float xv = xr[c * 64 + lane];
    const float* w = wr + (size_t)(c * 64 + lane) * 8;
    #pragma unroll
    for (int e = 0; e < 8; ++e) acc[e] = fmaf(xv, w[e], acc[e]);
  }
  #pragma unroll
  for (int off = 32; off; off >>= 1)
    #pragma unroll
    for (int e = 0; e < 8; ++e) acc[e] += __shfl_down(acc[e], off);
  if (lane == 0) {
    float mx = acc[0];
    #pragma unroll
    for (int e = 1; e < 8; ++e) mx = fmaxf(mx, acc[e]);
    float ex[8], sum = 0.0f;
    #pragma unroll
    for (int e = 0; e < 8; ++e) { ex[e] = expf(acc[e] - mx); sum += ex[e]; }
    int e1 = 0;
    #pragma unroll
    for (int e = 1; e < 8; ++e) if (acc[e] > acc[e1]) e1 = e;
    int e2 = (e1 == 0) ? 1 : 0;
    #pragma unroll
    for (int e = 0; e < 8; ++e) if (e != e1 && acc[e] > acc[e2]) e2 = e;
    const float g1v = ex[e1] / sum, g2v = ex[e2] / sum;
    int p1 = atomicAdd(&cnt[e1], 1);
    int p2 = atomicAdd(&cnt[e2], 1);
    if (p1 < CAP_) etok[e1 * CAP_ + p1] = t; else p1 = -1;
    if (p2 < CAP_) etok[e2 * CAP_ + p2] = t; else p2 = -1;
    tok_e[2*t] = e1;   tok_e[2*t+1] = e2;
    tok_g[2*t] = g1v;  tok_g[2*t+1] = g2v;
    tok_p[2*t] = p1;   tok_p[2*t+1] = p2;
  }
}

// --------------------------- gather tokens per expert (bf16) ---------------
__global__ __launch_bounds__(256) void gather_k(const u16* __restrict__ y2b,
                                                const int* __restrict__ etok,
                                                const int* __restrict__ cnt,
                                                u16* __restrict__ xe) {
  const int e = blockIdx.y, pos = blockIdx.x, tid = threadIdx.x;
  const int n = min(cnt[e], CAP_);
  ushort4* dst = (ushort4*)(xe + (size_t)(e * CAP_ + pos) * D_) + tid;
  if (pos < n) {
    const int t = etok[e * CAP_ + pos];
    *dst = ((const ushort4*)(y2b + (size_t)t * D_))[tid];
  } else {
    *dst = make_ushort4(0, 0, 0, 0);
  }
}

// --------------------------- bf16 MFMA GEMM: C = A * Bt^T ------------------
template<typename OT, bool RELU>
__global__ __launch_bounds__(256) void gemm_bt(const u16* __restrict__ A,
                                               const u16* __restrict__ Bt,
                                               OT* __restrict__ C,
                                               int M, int N, int K,
                                               int lda, int ldb, int ldc,
                                               long sAz, long sBz, long sCz) {
  __shared__ u16 As[128 * 32];
  __shared__ u16 Bs[128 * 32];
  const int tid = threadIdx.x;
  A  += (size_t)blockIdx.z * sAz;
  Bt += (size_t)blockIdx.z * sBz;
  C  += (size_t)blockIdx.z * sCz;
  const int bm = blockIdx.y, bn = blockIdx.x;
  const int lane = tid & 63, wave = tid >> 6;
  const int wy = wave >> 1, wx = wave & 1;
  const int l15 = lane & 15, lq = lane >> 4;
  const int ar = tid >> 1, ac = (tid & 1) * 16;
  f32x4 acc[4][4];
  #pragma unroll
  for (int i = 0; i < 4; ++i)
    #pragma unroll
    for (int j = 0; j < 4; ++j)
      #pragma unroll
      for (int r = 0; r < 4; ++r) acc[i][j][r] = 0.0f;
  const u16* Ag = A  + (size_t)(bm * 128 + ar) * lda + ac;
  const u16* Bg = Bt + (size_t)(bn * 128 + ar) * ldb + ac;

  for (int kt = 0; kt < K; kt += 32) {
    __syncthreads();
    *(ushort8v*)&As[ar * 32 + ac]     = *(const ushort8v*)(Ag + kt);
    *(ushort8v*)&As[ar * 32 + ac + 8] = *(const ushort8v*)(Ag + kt + 8);
    *(ushort8v*)&Bs[ar * 32 + ac]     = *(const ushort8v*)(Bg + kt);
    *(ushort8v*)&Bs[ar * 32 + ac + 8] = *(const ushort8v*)(Bg + kt + 8);
    __syncthreads();
    short8 a[4], b[4];
    #pragma unroll
    for (int i = 0; i < 4; ++i)
      a[i] = *(const short8*)&As[(wy * 64 + i * 16 + l15) * 32 + lq * 8];
    #pragma unroll
    for (int j = 0; j < 4; ++j)
      b[j] = *(const short8*)&Bs[(wx * 64 + j * 16 + l15) * 32 + lq * 8];
    #pragma unroll
    for (int i = 0; i < 4; ++i)
      #pragma unroll
      for (int j = 0; j < 4; ++j)
        acc[i][j] = __builtin_amdgcn_mfma_f32_16x16x32_bf16(a[i], b[j], acc[i][j], 0, 0, 0);
  }
  #pragma unroll
  for (int i = 0; i < 4; ++i)
    #pragma unroll
    for (int j = 0; j < 4; ++j)
      #pragma unroll
      for (int r = 0; r < 4; ++r) {
        const int row = bm * 128 + wy * 64 + i * 16 + lq * 4 + r;
        const int col = bn * 128 + wx * 64 + j * 16 + l15;
        float v = acc[i][j][r];
        if (RELU) v = fmaxf(v, 0.0f);
        cstore(C + (size_t)row * ldc + col, v);
      }
}

// --------------------------- weight transpose fp32 -> bf16^T ---------------
__global__ __launch_bounds__(256) void transpose_bf_k(const float* __restrict__ src,
                                                      u16* __restrict__ dst,
                                                      int R, int C) {
  __shared__ float tile[32][33];
  const int tid = threadIdx.x;
  const size_t zoff = (size_t)blockIdx.z * R * C;
  const int r0 = blockIdx.y * 32, c0 = blockIdx.x * 32;
  const int tx = tid & 31, ty = tid >> 5;
  #pragma unroll
  for (int i = 0; i < 4; ++i)
    tile[ty + i * 8][tx] = src[zoff + (size_t)(r0 + ty + i * 8) * C + c0 + tx];
  __syncthreads();
  #pragma unroll
  for (int i = 0; i < 4; ++i)
    dst[zoff + (size_t)(c0 + ty + i * 8) * R + r0 + tx] = f2bf(tile[tx][ty + i * 8]);
}

// --------------------------- final combine ---------------------------------
__global__ __launch_bounds__(256) void combine_k(const float* __restrict__ x2,
                                                 const float* __restrict__ ye,
                                                 const int*   __restrict__ tok_e,
                                                 const float* __restrict__ tok_g,
                                                 const int*   __restrict__ tok_p,
                                                 float* __restrict__ out) {
  const int t = blockIdx.x, tid = threadIdx.x;
  float4 v = ((const float4*)(x2 + (size_t)t * D_))[tid];
  #pragma unroll
  for (int r = 0; r < 2; ++r) {
    const int p = tok_p[2 * t + r];
    if (p >= 0) {
      const int e = tok_e[2 * t + r];
      const float g = tok_g[2 * t + r];
      const float4 y = ((const float4*)(ye + (size_t)(e * CAP_ + p) * D_))[tid];
      v.x = fmaf(g, y.x, v.x);
      v.y = fmaf(g, y.y, v.y);
      v.z = fmaf(g, y.z, v.z);
      v.w = fmaf(g, y.w, v.w);
    }
  }
  ((float4*)(out + (size_t)t * D_))[tid] = v;
}

// ---------------------------------------------------------------------------
extern "C" void kernel_launch(void* const* d_in, const int* in_sizes, int n_in,
                              void* d_out, int out_size, void* d_ws, size_t ws_size,
                              hipStream_t stream) {
  const float* x    = (const float*)d_in[0];
  const float* g1   = (const float*)d_in[1];
  const float* wqkv = (const float*)d_in[2];
  const float* wo   = (const float*)d_in[3];
  const float* g2   = (const float*)d_in[4];
  const float* wr   = (const float*)d_in[5];
  const float* w1   = (const float*)d_in[6];
  const float* w2   = (const float*)d_in[7];
  float* out = (float*)d_out;
  char* ws = (char*)d_ws;
  const size_t MB = 1ull << 20;

  // Phase-aliased workspace layout (~233 MB):
  float* y1    = (float*)(ws + 0);          // 16MB, dead after QKV GEMM
  u16*   qhi   = (u16*)  (ws + 0);          // 8MB  (aliases y1; written after)
  u16*   qlo   = (u16*)  (ws + 8 * MB);     // 8MB
  float* attnf = (float*)(ws + 16 * MB);    // 16MB, dead after out-proj
  u16*   hbf   = (u16*)  (ws + 0);          // 40MB, MoE hidden (after attention)
  float* qkv   = (float*)(ws + 40 * MB);    // 48MB, dead after rope/v split
  u16*   xe    = (u16*)  (ws + 40 * MB);    // 20MB, aliases qkv (MoE time)
  float* x2    = (float*)(ws + 88 * MB);    // 16MB
  float* y2    = (float*)(ws + 104 * MB);   // 16MB (fp32 for router!)
  u16*   y2b   = (u16*)  (ws + 120 * MB);   // 8MB
  u16*   w1t   = (u16*)  (ws + 128 * MB);   // 32MB  [E][FFN][D] bf16
  u16*   w2t   = (u16*)  (ws + 160 * MB);   // 32MB  [E][D][FFN] bf16
  float* ye    = (float*)(ws + 192 * MB);   // 40MB (MoE time)
  u16*   khi   = (u16*)  (ws + 192 * MB);   // 8MB  (aliases ye; dead before MoE)
  u16*   klo   = (u16*)  (ws + 200 * MB);   // 8MB
  u16*   vthi  = (u16*)  (ws + 208 * MB);   // 8MB
  u16*   vtlo  = (u16*)  (ws + 216 * MB);   // 8MB
  int*   cnt   = (int*)  (ws + 232 * MB);
  int*   tok_e = cnt + 16;                  // 2*T
  float* tok_g = (float*)(tok_e + 2 * T_);  // 2*T
  int*   tok_p = (int*)  (tok_g + 2 * T_);  // 2*T
  int*   etok  = tok_p + 2 * T_;            // E*CAP

  init_k<<<1, 64, 0, stream>>>(cnt);
  transpose_bf_k<<<dim3(FFN_/32, D_/32, E_), 256, 0, stream>>>(w1, w1t, D_, FFN_);
  transpose_bf_k<<<dim3(D_/32, FFN_/32, E_), 256, 0, stream>>>(w2, w2t, FFN_, D_);

  // x -> rmsnorm -> y1 (fp32)
  rmsnorm_k<<<T_, 256, 0, stream>>>(x, g1, y1, (u16*)nullptr);
  // y1 @ w_qkv -> qkv (fp32)
  gemm_f32<false><<<dim3(3 * D_ / 128, T_ / 128), 256, 0, stream>>>(
      y1, wqkv, nullptr, qkv, T_, 3 * D_, D_, D_, 3 * D_, 3 * D_);
  // RoPE + split q,k (q pre-scaled by 1/8); transpose + split v
  ropesplit_k<<<T_ * H_ * 32 / 256, 256, 0, stream>>>(qkv, qhi, qlo, khi, klo);
  vsplit_k<<<dim3(S_ / 64, B_ * H_), 256, 0, stream>>>(qkv, vthi, vtlo);
  // split-bf16 MFMA flash attention -> attnf [B,S,D] fp32
  attn_mfma_k<<<dim3(S_ / 64, B_ * H_), 256, 0, stream>>>(
      qhi, qlo, khi, klo, vthi, vtlo, attnf);
  // attnf @ w_o + x -> x2
  gemm_f32<true><<<dim3(D_ / 128, T_ / 128), 256, 0, stream>>>(
      attnf, wo, x, x2, T_, D_, D_, D_, D_, D_);
  // x2 -> rmsnorm -> y2 (fp32) + y2b (bf16)
  rmsnorm_k<<<T_, 256, 0, stream>>>(x2, g2, y2, y2b);
  // router (fp32 logits, top-2, capacity assignment)
  router_k<<<T_ / 4, 256, 0, stream>>>(y2, wr, cnt, tok_e, tok_g, tok_p, etok);
  // gather per-expert token rows (bf16)
  gather_k<<<dim3(CAP_, E_), 256, 0, stream>>>(y2b, etok, cnt, xe);
  // h = relu(xe @ w1) (bf16 out), batched over experts
  gemm_bt<u16, true><<<dim3(FFN_/128, CAP_/128, E_), 256, 0, stream>>>(
      xe, w1t, hbf, CAP_, FFN_, D_, D_, D_, FFN_,
      (long)CAP_ * D_, (long)FFN_ * D_, (long)CAP_ * FFN_);
  // ye = h @ w2 (fp32 out)
  gemm_bt<float, false><<<dim3(D_/128, CAP_/128, E_), 256, 0, stream>>>(
      hbf, w2t, ye, CAP_, D_, FFN_, FFN_, FFN_, D_,
      (long)CAP_ * FFN_, (long)D_ * FFN_, (long)CAP_ * D_);
  // out = x2 + sum_r gate_r * ye[...]
  combine_k<<<T_, 256, 0, stream>>>(x2, ye, tok_e, tok_g, tok_p, out);
}

// Round 3
// 843.108 us; speedup vs baseline: 2.8876x; 1.4036x over previous
//
#include <hip/hip_runtime.h>
#include <math.h>

// ---------------------------------------------------------------------------
// Fused transformer block on MI355X.
// Precision strategy: everything feeding the MoE router must match fp32
// closely (min top-2 logit gap ~3e-5 over 4096 tokens).
//  - Attention: split-bf16 MFMA (hh+hl+lh), ~2^-17 rel error. Validated R2.
//  - QKV / out-proj GEMMs: split-fp16 MFMA (hh+hl+lh). fp16 keeps 11 mantissa
//    bits -> dropped ll term ~2^-24 rel: fp32-equivalent, routing exact.
//  - Post-routing MoE GEMMs: plain bf16 MFMA.
// ---------------------------------------------------------------------------

#define B_   2
#define S_   2048
#define D_   1024
#define H_   16
#define HD_  64
#define FFN_ 2048
#define E_   8
#define CAP_ 1280
#define T_   (B_*S_)

typedef unsigned short u16;
typedef __attribute__((ext_vector_type(8))) short     short8;    // MFMA bf16x8 operand
typedef __attribute__((ext_vector_type(8))) _Float16  half8;     // MFMA f16x8 operand
typedef __attribute__((ext_vector_type(8))) unsigned short ushort8v;
typedef __attribute__((ext_vector_type(4))) float     f32x4;

__device__ __forceinline__ u16 f2bf(float f) {
  unsigned u = __float_as_uint(f);
  return (u16)((u + 0x7fffu + ((u >> 16) & 1u)) >> 16);   // RNE
}
__device__ __forceinline__ float bf2f(u16 h) {
  return __uint_as_float(((unsigned)h) << 16);
}
__device__ __forceinline__ u16 f2h(float f) {
  _Float16 h = (_Float16)f;
  return __builtin_bit_cast(u16, h);
}
__device__ __forceinline__ float h2f(u16 b) {
  return (float)__builtin_bit_cast(_Float16, b);
}

__device__ __forceinline__ void cstore(float* p, float v) { *p = v; }
__device__ __forceinline__ void cstore(u16* p, float v)   { *p = f2bf(v); }

// --------------------------- init: zero expert counters --------------------
__global__ void init_k(int* cnt) {
  if (threadIdx.x < 16) cnt[threadIdx.x] = 0;
}

// --------------------------- RMSNorm (fp32 in; fp32/bf16/fp16-split out) ---
__global__ __launch_bounds__(256) void rmsnorm_k(const float* __restrict__ x,
                                                 const float* __restrict__ g,
                                                 float* __restrict__ of,
                                                 u16*   __restrict__ ob,
                                                 u16*   __restrict__ ohh,
                                                 u16*   __restrict__ ohl) {
  const int t = blockIdx.x, tid = threadIdx.x;
  const float4 xv = ((const float4*)(x + (size_t)t * D_))[tid];
  float ss = xv.x*xv.x + xv.y*xv.y + xv.z*xv.z + xv.w*xv.w;
  #pragma unroll
  for (int off = 32; off; off >>= 1) ss += __shfl_down(ss, off);
  __shared__ float wsum[4];
  if ((tid & 63) == 0) wsum[tid >> 6] = ss;
  __syncthreads();
  const float tot = wsum[0] + wsum[1] + wsum[2] + wsum[3];
  const float rms = 1.0f / sqrtf(tot * (1.0f / D_) + 1e-6f);
  const float4 gv = ((const float4*)g)[tid];
  float4 o;
  o.x = gv.x * xv.x * rms;
  o.y = gv.y * xv.y * rms;
  o.z = gv.z * xv.z * rms;
  o.w = gv.w * xv.w * rms;
  if (of) ((float4*)(of + (size_t)t * D_))[tid] = o;
  if (ob) {
    ushort4 h;
    h.x = f2bf(o.x); h.y = f2bf(o.y); h.z = f2bf(o.z); h.w = f2bf(o.w);
    ((ushort4*)(ob + (size_t)t * D_))[tid] = h;
  }
  if (ohh) {
    ushort4 hh, hl;
    hh.x = f2h(o.x); hl.x = f2h(o.x - h2f(hh.x));
    hh.y = f2h(o.y); hl.y = f2h(o.y - h2f(hh.y));
    hh.z = f2h(o.z); hl.z = f2h(o.z - h2f(hh.z));
    hh.w = f2h(o.w); hl.w = f2h(o.w - h2f(hh.w));
    ((ushort4*)(ohh + (size_t)t * D_))[tid] = hh;
    ((ushort4*)(ohl + (size_t)t * D_))[tid] = hl;
  }
}

// --------------------------- split-fp16 MFMA GEMM: C = (A)(Bt)^T (+resid) --
// A hi/lo: MxK fp16-bits row-major (lda). Bt hi/lo: NxK (ldb).
// 128x128 tile, BK=32, 4 waves 2x2, 3 MFMA products (hh, hl, lh) per tile.
template<bool RESID>
__global__ __launch_bounds__(256) void gemm_split(const u16* __restrict__ Ah,
                                                  const u16* __restrict__ Al,
                                                  const u16* __restrict__ Bh,
                                                  const u16* __restrict__ Bl,
                                                  const float* __restrict__ resid,
                                                  float* __restrict__ C,
                                                  int K, int lda, int ldb, int ldc) {
  __shared__ u16 AsH[128 * 32], AsL[128 * 32];
  __shared__ u16 BsH[128 * 32], BsL[128 * 32];
  const int tid = threadIdx.x;
  const int bm = blockIdx.y, bn = blockIdx.x;
  const int lane = tid & 63, wave = tid >> 6;
  const int wy = wave >> 1, wx = wave & 1;
  const int l15 = lane & 15, lq = lane >> 4;
  const int ar = tid >> 1, ac = (tid & 1) * 16;
  f32x4 acc[4][4];
  #pragma unroll
  for (int i = 0; i < 4; ++i)
    #pragma unroll
    for (int j = 0; j < 4; ++j)
      #pragma unroll
      for (int r = 0; r < 4; ++r) acc[i][j][r] = 0.0f;
  const size_t aoff = (size_t)(bm * 128 + ar) * lda + ac;
  const size_t boff = (size_t)(bn * 128 + ar) * ldb + ac;

  for (int kt = 0; kt < K; kt += 32) {
    __syncthreads();
    *(ushort8v*)&AsH[ar * 32 + ac]     = *(const ushort8v*)(Ah + aoff + kt);
    *(ushort8v*)&AsH[ar * 32 + ac + 8] = *(const ushort8v*)(Ah + aoff + kt + 8);
    *(ushort8v*)&AsL[ar * 32 + ac]     = *(const ushort8v*)(Al + aoff + kt);
    *(ushort8v*)&AsL[ar * 32 + ac + 8] = *(const ushort8v*)(Al + aoff + kt + 8);
    *(ushort8v*)&BsH[ar * 32 + ac]     = *(const ushort8v*)(Bh + boff + kt);
    *(ushort8v*)&BsH[ar * 32 + ac + 8] = *(const ushort8v*)(Bh + boff + kt + 8);
    *(ushort8v*)&BsL[ar * 32 + ac]     = *(const ushort8v*)(Bl + boff + kt);
    *(ushort8v*)&BsL[ar * 32 + ac + 8] = *(const ushort8v*)(Bl + boff + kt + 8);
    __syncthreads();
    half8 ah[4], al[4], bh[4], bl[4];
    #pragma unroll
    for (int i = 0; i < 4; ++i) {
      const int row = (wy * 64 + i * 16 + l15) * 32 + lq * 8;
      ah[i] = *(const half8*)&AsH[row];
      al[i] = *(const half8*)&AsL[row];
    }
    #pragma unroll
    for (int j = 0; j < 4; ++j) {
      const int row = (wx * 64 + j * 16 + l15) * 32 + lq * 8;
      bh[j] = *(const half8*)&BsH[row];
      bl[j] = *(const half8*)&BsL[row];
    }
    #pragma unroll
    for (int i = 0; i < 4; ++i)
      #pragma unroll
      for (int j = 0; j < 4; ++j) {
        acc[i][j] = __builtin_amdgcn_mfma_f32_16x16x32_f16(ah[i], bh[j], acc[i][j], 0, 0, 0);
        acc[i][j] = __builtin_amdgcn_mfma_f32_16x16x32_f16(ah[i], bl[j], acc[i][j], 0, 0, 0);
        acc[i][j] = __builtin_amdgcn_mfma_f32_16x16x32_f16(al[i], bh[j], acc[i][j], 0, 0, 0);
      }
  }
  #pragma unroll
  for (int i = 0; i < 4; ++i)
    #pragma unroll
    for (int j = 0; j < 4; ++j)
      #pragma unroll
      for (int r = 0; r < 4; ++r) {
        const int row = bm * 128 + wy * 64 + i * 16 + lq * 4 + r;
        const int col = bn * 128 + wx * 64 + j * 16 + l15;
        float v = acc[i][j][r];
        if (RESID) v += resid[(size_t)row * ldc + col];
        C[(size_t)row * ldc + col] = v;
      }
}

// --------------------------- weight transpose + fp16 split -----------------
// src [R][C] fp32 -> dst hi/lo [C][R] fp16-bits
__global__ __launch_bounds__(256) void wsplit_t_k(const float* __restrict__ src,
                                                  u16* __restrict__ dh,
                                                  u16* __restrict__ dl,
                                                  int R, int C) {
  __shared__ float tile[32][33];
  const int tid = threadIdx.x;
  const int r0 = blockIdx.y * 32, c0 = blockIdx.x * 32;
  const int tx = tid & 31, ty = tid >> 5;
  #pragma unroll
  for (int i = 0; i < 4; ++i)
    tile[ty + i * 8][tx] = src[(size_t)(r0 + ty + i * 8) * C + c0 + tx];
  __syncthreads();
  #pragma unroll
  for (int i = 0; i < 4; ++i) {
    const float v = tile[tx][ty + i * 8];
    const u16 hh = f2h(v);
    const size_t o = (size_t)(c0 + ty + i * 8) * R + r0 + tx;
    dh[o] = hh;
    dl[o] = f2h(v - h2f(hh));
  }
}

// --------------------------- RoPE + split q,k -> bf16 hi/lo ----------------
__global__ __launch_bounds__(256) void ropesplit_k(const float* __restrict__ qkv,
                                                   u16* __restrict__ qhi, u16* __restrict__ qlo,
                                                   u16* __restrict__ khi, u16* __restrict__ klo) {
  const int i = blockIdx.x * 256 + threadIdx.x;   // over T_*H_*32
  const int j = i & 31;
  const int h = (i >> 5) & 15;
  const int t = i >> 9;
  const int s = t & (S_ - 1);
  const int b = t >> 11;
  const int bh = b * 16 + h;
  const float theta = (float)pow(10000.0, -(double)j / 32.0);
  const float fr = (float)s * theta;
  const float c = cosf(fr), sn = sinf(fr);
  const float2 q = *(const float2*)(qkv + (size_t)t * 3072 + h * 64 + 2 * j);
  const float2 k = *(const float2*)(qkv + (size_t)t * 3072 + 1024 + h * 64 + 2 * j);
  const float q0 = (q.x * c - q.y * sn) * 0.125f;
  const float q1 = (q.x * sn + q.y * c) * 0.125f;
  const float k0 = k.x * c - k.y * sn;
  const float k1 = k.x * sn + k.y * c;
  const size_t o = ((size_t)bh * S_ + s) * 32 + j;   // uint (2xu16) index
  const u16 qh0 = f2bf(q0), qh1 = f2bf(q1);
  const u16 kh0 = f2bf(k0), kh1 = f2bf(k1);
  ((unsigned*)qhi)[o] = (unsigned)qh0 | ((unsigned)qh1 << 16);
  ((unsigned*)khi)[o] = (unsigned)kh0 | ((unsigned)kh1 << 16);
  const u16 ql0 = f2bf(q0 - bf2f(qh0)), ql1 = f2bf(q1 - bf2f(qh1));
  const u16 kl0 = f2bf(k0 - bf2f(kh0)), kl1 = f2bf(k1 - bf2f(kh1));
  ((unsigned*)qlo)[o] = (unsigned)ql0 | ((unsigned)ql1 << 16);
  ((unsigned*)klo)[o] = (unsigned)kl0 | ((unsigned)kl1 << 16);
}

// --------------------------- V: transpose + split -> [bh][d][s] bf16 -------
__global__ __launch_bounds__(256) void vsplit_k(const float* __restrict__ qkv,
                                                u16* __restrict__ vthi,
                                                u16* __restrict__ vtlo) {
  __shared__ float tile[64][65];
  const int st = blockIdx.x, bh = blockIdx.y;
  const int b = bh >> 4, h = bh & 15;
  const int tid = threadIdx.x;
  const int c = tid & 63, r4 = tid >> 6;
  #pragma unroll
  for (int i = 0; i < 16; ++i) {
    const int r = i * 4 + r4;
    tile[r][c] = qkv[(size_t)(b * S_ + st * 64 + r) * 3072 + 2048 + h * 64 + c];
  }
  __syncthreads();
  #pragma unroll
  for (int i = 0; i < 16; ++i) {
    const int d = i * 4 + r4;
    const float v = tile[c][d];
    const u16 hi = f2bf(v);
    const size_t o = ((size_t)bh * 64 + d) * S_ + st * 64 + c;
    vthi[o] = hi;
    vtlo[o] = f2bf(v - bf2f(hi));
  }
}

// --------------------------- split-bf16 MFMA flash attention ---------------
// Block: 64-query tile x one (b,h). 4 waves, 16 query rows each.
// Output: fp16 hi/lo (A-operand form for the out-proj split GEMM).
__global__ __launch_bounds__(256) void attn_mfma_k(const u16* __restrict__ qhi,
                                                   const u16* __restrict__ qlo,
                                                   const u16* __restrict__ khi,
                                                   const u16* __restrict__ klo,
                                                   const u16* __restrict__ vthi,
                                                   const u16* __restrict__ vtlo,
                                                   u16* __restrict__ ahh,
                                                   u16* __restrict__ ahl) {
  __shared__ u16 Kh[64 * 68], Kl[64 * 68];   // [key][dim]
  __shared__ u16 Vh[64 * 68], Vl[64 * 68];   // [dim][key]
  __shared__ u16 Ph[4][16 * 68], Pl[4][16 * 68];  // per-wave P round-trip
  const int tid = threadIdx.x, lane = tid & 63, wave = tid >> 6;
  const int qt = gridDim.x - 1 - blockIdx.x;   // longest blocks dispatch first
  const int bh = blockIdx.y;
  const int l15 = lane & 15, lq = lane >> 4;
  const size_t hb = (size_t)bh * S_ * 64;
  const int qrow = qt * 64 + wave * 16 + l15;
  short8 qh[2], ql[2];
  qh[0] = *(const short8*)(qhi + hb + (size_t)qrow * 64 + lq * 8);
  qh[1] = *(const short8*)(qhi + hb + (size_t)qrow * 64 + 32 + lq * 8);
  ql[0] = *(const short8*)(qlo + hb + (size_t)qrow * 64 + lq * 8);
  ql[1] = *(const short8*)(qlo + hb + (size_t)qrow * 64 + 32 + lq * 8);
  f32x4 O[4];
  float m_i[4], l_i[4];
  #pragma unroll
  for (int n = 0; n < 4; ++n)
    #pragma unroll
    for (int r = 0; r < 4; ++r) O[n][r] = 0.0f;
  #pragma unroll
  for (int r = 0; r < 4; ++r) { m_i[r] = -__builtin_inff(); l_i[r] = 0.0f; }

  for (int kt = 0; kt <= qt; ++kt) {
    __syncthreads();
    #pragma unroll
    for (int it = 0; it < 2; ++it) {
      const int idx = it * 256 + tid;
      const int row = idx >> 3, c8 = (idx & 7) * 8;
      const size_t koff = hb + (size_t)(kt * 64 + row) * 64 + c8;
      *(ushort8v*)&Kh[row * 68 + c8] = *(const ushort8v*)(khi + koff);
      *(ushort8v*)&Kl[row * 68 + c8] = *(const ushort8v*)(klo + koff);
      const size_t voff = ((size_t)bh * 64 + row) * S_ + kt * 64 + c8;
      *(ushort8v*)&Vh[row * 68 + c8] = *(const ushort8v*)(vthi + voff);
      *(ushort8v*)&Vl[row * 68 + c8] = *(const ushort8v*)(vtlo + voff);
    }
    __syncthreads();
    // ---- S = Q K^T (3-product split) ----
    f32x4 sc[4];
    #pragma unroll
    for (int n = 0; n < 4; ++n)
      #pragma unroll
      for (int r = 0; r < 4; ++r) sc[n][r] = 0.0f;
    #pragma unroll
    for (int n = 0; n < 4; ++n) {
      const int krow = (n * 16 + l15) * 68 + lq * 8;
      const short8 kb0 = *(const short8*)&Kh[krow];
      const short8 kb1 = *(const short8*)&Kh[krow + 32];
      const short8 kl0 = *(const short8*)&Kl[krow];
      const short8 kl1 = *(const short8*)&Kl[krow + 32];
      sc[n] = __builtin_amdgcn_mfma_f32_16x16x32_bf16(qh[0], kb0, sc[n], 0, 0, 0);
      sc[n] = __builtin_amdgcn_mfma_f32_16x16x32_bf16(qh[1], kb1, sc[n], 0, 0, 0);
      sc[n] = __builtin_amdgcn_mfma_f32_16x16x32_bf16(qh[0], kl0, sc[n], 0, 0, 0);
      sc[n] = __builtin_amdgcn_mfma_f32_16x16x32_bf16(qh[1], kl1, sc[n], 0, 0, 0);
      sc[n] = __builtin_amdgcn_mfma_f32_16x16x32_bf16(ql[0], kb0, sc[n], 0, 0, 0);
      sc[n] = __builtin_amdgcn_mfma_f32_16x16x32_bf16(ql[1], kb1, sc[n], 0, 0, 0);
    }
    // ---- causal mask on the diagonal tile ----
    if (kt == qt) {
      #pragma unroll
      for (int n = 0; n < 4; ++n)
        #pragma unroll
        for (int r = 0; r < 4; ++r)
          if (n * 16 + l15 > wave * 16 + lq * 4 + r) sc[n][r] = -__builtin_inff();
    }
    // ---- online softmax (rows live across 16 lanes l15, per reg r) ----
    float al[4];
    #pragma unroll
    for (int r = 0; r < 4; ++r) {
      float mx = fmaxf(fmaxf(sc[0][r], sc[1][r]), fmaxf(sc[2][r], sc[3][r]));
      mx = fmaxf(mx, __shfl_xor(mx, 1));
      mx = fmaxf(mx, __shfl_xor(mx, 2));
      mx = fmaxf(mx, __shfl_xor(mx, 4));
      mx = fmaxf(mx, __shfl_xor(mx, 8));
      const float mn = fmaxf(m_i[r], mx);
      al[r] = __expf(m_i[r] - mn);
      m_i[r] = mn;
    }
    f32x4 p[4];
    #pragma unroll
    for (int n = 0; n < 4; ++n)
      #pragma unroll
      for (int r = 0; r < 4; ++r) p[n][r] = __expf(sc[n][r] - m_i[r]);
    #pragma unroll
    for (int r = 0; r < 4; ++r) {
      float rs = p[0][r] + p[1][r] + p[2][r] + p[3][r];
      rs += __shfl_xor(rs, 1);
      rs += __shfl_xor(rs, 2);
      rs += __shfl_xor(rs, 4);
      rs += __shfl_xor(rs, 8);
      l_i[r] = l_i[r] * al[r] + rs;
      O[0][r] *= al[r]; O[1][r] *= al[r]; O[2][r] *= al[r]; O[3][r] *= al[r];
    }
    // ---- P: C-layout regs -> LDS in A-layout, split hi/lo ----
    #pragma unroll
    for (int n = 0; n < 4; ++n)
      #pragma unroll
      for (int r = 0; r < 4; ++r) {
        const float v = p[n][r];
        const u16 hi = f2bf(v);
        const int a = (lq * 4 + r) * 68 + n * 16 + l15;
        Ph[wave][a] = hi;
        Pl[wave][a] = f2bf(v - bf2f(hi));
      }
    asm volatile("s_waitcnt lgkmcnt(0)" ::: "memory");
    short8 pah[2], pal[2];
    pah[0] = *(const short8*)&Ph[wave][l15 * 68 + lq * 8];
    pah[1] = *(const short8*)&Ph[wave][l15 * 68 + 32 + lq * 8];
    pal[0] = *(const short8*)&Pl[wave][l15 * 68 + lq * 8];
    pal[1] = *(const short8*)&Pl[wave][l15 * 68 + 32 + lq * 8];
    // ---- O += P V (3-product split); V in LDS is [dim][key] = B^T layout --
    #pragma unroll
    for (int n = 0; n < 4; ++n) {
      const int vrow = (n * 16 + l15) * 68 + lq * 8;
      const short8 vb0 = *(const short8*)&Vh[vrow];
      const short8 vb1 = *(const short8*)&Vh[vrow + 32];
      const short8 vl0 = *(const short8*)&Vl[vrow];
      const short8 vl1 = *(const short8*)&Vl[vrow + 32];
      O[n] = __builtin_amdgcn_mfma_f32_16x16x32_bf16(pah[0], vb0, O[n], 0, 0, 0);
      O[n] = __builtin_amdgcn_mfma_f32_16x16x32_bf16(pah[1], vb1, O[n], 0, 0, 0);
      O[n] = __builtin_amdgcn_mfma_f32_16x16x32_bf16(pah[0], vl0, O[n], 0, 0, 0);
      O[n] = __builtin_amdgcn_mfma_f32_16x16x32_bf16(pah[1], vl1, O[n], 0, 0, 0);
      O[n] = __builtin_amdgcn_mfma_f32_16x16x32_bf16(pal[0], vb0, O[n], 0, 0, 0);
      O[n] = __builtin_amdgcn_mfma_f32_16x16x32_bf16(pal[1], vb1, O[n], 0, 0, 0);
    }
  }
  const int b = bh >> 4, h = bh & 15;
  #pragma unroll
  for (int r = 0; r < 4; ++r) {
    const float inv = 1.0f / l_i[r];
    const int row = qt * 64 + wave * 16 + lq * 4 + r;
    const size_t base = (size_t)(b * S_ + row) * D_ + h * 64 + l15;
    #pragma unroll
    for (int n = 0; n < 4; ++n) {
      const float o = O[n][r] * inv;
      const u16 hh = f2h(o);
      ahh[base + n * 16] = hh;
      ahl[base + n * 16] = f2h(o - h2f(hh));
    }
  }
}

// --------------------------- router: logits + top2 + capacity assign -------
__global__ __launch_bounds__(256) void router_k(const float* __restrict__ y2,
                                                const float* __restrict__ wr,
                                                int*   __restrict__ cnt,
                                                int*   __restrict__ tok_e,
                                                float* __restrict__ tok_g,
                                                int*   __restrict__ tok_p,
                                                int*   __restrict__ etok) {
  const int wave = threadIdx.x >> 6, lane = threadIdx.x & 63;
  const int t = blockIdx.x * 4 + wave;
  const float* xr = y2 + (size_t)t * D_;
  float acc[8];
  #pragma unroll
  for (int e = 0; e < 8; ++e) acc[e] = 0.0f;
  for (int c = 0; c < 16; ++c) {
    const float xv = xr[c * 64 + lane];
    const float* w = wr + (size_t)(c * 64 + lane) * 8;
    #pragma unroll
    for (int e = 0; e < 8; ++e) acc[e] = fmaf(xv, w[e], acc[e]);
  }
  #pragma unroll
  for (int off = 32; off; off >>= 1)
    #pragma unroll
    for (int e = 0; e < 8; ++e) acc[e] += __shfl_down(acc[e], off);
  if (lane == 0) {
    float mx = acc[0];
    #pragma unroll
    for (int e = 1; e < 8; ++e) mx = fmaxf(mx, acc[e]);
    float ex[8], sum = 0.0f;
    #pragma unroll
    for (int e = 0; e < 8; ++e) { ex[e] = expf(acc[e] - mx); sum += ex[e]; }
    int e1 = 0;
    #pragma unroll
    for (int e = 1; e < 8; ++e) if (acc[e] > acc[e1]) e1 = e;
    int e2 = (e1 == 0) ? 1 : 0;
    #pragma unroll
    for (int e = 0; e < 8; ++e) if (e != e1 && acc[e] > acc[e2]) e2 = e;
    const float g1v = ex[e1] / sum, g2v = ex[e2] / sum;
    int p1 = atomicAdd(&cnt[e1], 1);
    int p2 = atomicAdd(&cnt[e2], 1);
    if (p1 < CAP_) etok[e1 * CAP_ + p1] = t; else p1 = -1;
    if (p2 < CAP_) etok[e2 * CAP_ + p2] = t; else p2 = -1;
    tok_e[2*t] = e1;   tok_e[2*t+1] = e2;
    tok_g[2*t] = g1v;  tok_g[2*t+1] = g2v;
    tok_p[2*t] = p1;   tok_p[2*t+1] = p2;
  }
}

// --------------------------- gather tokens per expert (bf16) ---------------
__global__ __launch_bounds__(256) void gather_k(const u16* __restrict__ y2b,
                                                const int* __restrict__ etok,
                                                const int* __restrict__ cnt,
                                                u16* __restrict__ xe) {
  const int e = blockIdx.y, pos = blockIdx.x, tid = threadIdx.x;
  const int n = min(cnt[e], CAP_);
  ushort4* dst = (ushort4*)(xe + (size_t)(e * CAP_ + pos) * D_) + tid;
  if (pos < n) {
    const int t = etok[e * CAP_ + pos];
    *dst = ((const ushort4*)(y2b + (size_t)t * D_))[tid];
  } else {
    *dst = make_ushort4(0, 0, 0, 0);
  }
}

// --------------------------- bf16 MFMA GEMM: C = A * Bt^T ------------------
template<typename OT, bool RELU>
__global__ __launch_bounds__(256) void gemm_bt(const u16* __restrict__ A,
                                               const u16* __restrict__ Bt,
                                               OT* __restrict__ C,
                                               int M, int N, int K,
                                               int lda, int ldb, int ldc,
                                               long sAz, long sBz, long sCz) {
  __shared__ u16 As[128 * 32];
  __shared__ u16 Bs[128 * 32];
  const int tid = threadIdx.x;
  A  += (size_t)blockIdx.z * sAz;
  Bt += (size_t)blockIdx.z * sBz;
  C  += (size_t)blockIdx.z * sCz;
  const int bm = blockIdx.y, bn = blockIdx.x;
  const int lane = tid & 63, wave = tid >> 6;
  const int wy = wave >> 1, wx = wave & 1;
  const int l15 = lane & 15, lq = lane >> 4;
  const int ar = tid >> 1, ac = (tid & 1) * 16;
  f32x4 acc[4][4];
  #pragma unroll
  for (int i = 0; i < 4; ++i)
    #pragma unroll
    for (int j = 0; j < 4; ++j)
      #pragma unroll
      for (int r = 0; r < 4; ++r) acc[i][j][r] = 0.0f;
  const u16* Ag = A  + (size_t)(bm * 128 + ar) * lda + ac;
  const u16* Bg = Bt + (size_t)(bn * 128 + ar) * ldb + ac;

  for (int kt = 0; kt < K; kt += 32) {
    __syncthreads();
    *(ushort8v*)&As[ar * 32 + ac]     = *(const ushort8v*)(Ag + kt);
    *(ushort8v*)&As[ar * 32 + ac + 8] = *(const ushort8v*)(Ag + kt + 8);
    *(ushort8v*)&Bs[ar * 32 + ac]     = *(const ushort8v*)(Bg + kt);
    *(ushort8v*)&Bs[ar * 32 + ac + 8] = *(const ushort8v*)(Bg + kt + 8);
    __syncthreads();
    short8 a[4], b[4];
    #pragma unroll
    for (int i = 0; i < 4; ++i)
      a[i] = *(const short8*)&As[(wy * 64 + i * 16 + l15) * 32 + lq * 8];
    #pragma unroll
    for (int j = 0; j < 4; ++j)
      b[j] = *(const short8*)&Bs[(wx * 64 + j * 16 + l15) * 32 + lq * 8];
    #pragma unroll
    for (int i = 0; i < 4; ++i)
      #pragma unroll
      for (int j = 0; j < 4; ++j)
        acc[i][j] = __builtin_amdgcn_mfma_f32_16x16x32_bf16(a[i], b[j], acc[i][j], 0, 0, 0);
  }
  #pragma unroll
  for (int i = 0; i < 4; ++i)
    #pragma unroll
    for (int j = 0; j < 4; ++j)
      #pragma unroll
      for (int r = 0; r < 4; ++r) {
        const int row = bm * 128 + wy * 64 + i * 16 + lq * 4 + r;
        const int col = bn * 128 + wx * 64 + j * 16 + l15;
        float v = acc[i][j][r];
        if (RELU) v = fmaxf(v, 0.0f);
        cstore(C + (size_t)row * ldc + col, v);
      }
}

// --------------------------- weight transpose fp32 -> bf16^T ---------------
__global__ __launch_bounds__(256) void transpose_bf_k(const float* __restrict__ src,
                                                      u16* __restrict__ dst,
                                                      int R, int C) {
  __shared__ float tile[32][33];
  const int tid = threadIdx.x;
  const size_t zoff = (size_t)blockIdx.z * R * C;
  const int r0 = blockIdx.y * 32, c0 = blockIdx.x * 32;
  const int tx = tid & 31, ty = tid >> 5;
  #pragma unroll
  for (int i = 0; i < 4; ++i)
    tile[ty + i * 8][tx] = src[zoff + (size_t)(r0 + ty + i * 8) * C + c0 + tx];
  __syncthreads();
  #pragma unroll
  for (int i = 0; i < 4; ++i)
    dst[zoff + (size_t)(c0 + ty + i * 8) * R + r0 + tx] = f2bf(tile[tx][ty + i * 8]);
}

// --------------------------- final combine ---------------------------------
__global__ __launch_bounds__(256) void combine_k(const float* __restrict__ x2,
                                                 const float* __restrict__ ye,
                                                 const int*   __restrict__ tok_e,
                                                 const float* __restrict__ tok_g,
                                                 const int*   __restrict__ tok_p,
                                                 float* __restrict__ out) {
  const int t = blockIdx.x, tid = threadIdx.x;
  float4 v = ((const float4*)(x2 + (size_t)t * D_))[tid];
  #pragma unroll
  for (int r = 0; r < 2; ++r) {
    const int p = tok_p[2 * t + r];
    if (p >= 0) {
      const int e = tok_e[2 * t + r];
      const float g = tok_g[2 * t + r];
      const float4 y = ((const float4*)(ye + (size_t)(e * CAP_ + p) * D_))[tid];
      v.x = fmaf(g, y.x, v.x);
      v.y = fmaf(g, y.y, v.y);
      v.z = fmaf(g, y.z, v.z);
      v.w = fmaf(g, y.w, v.w);
    }
  }
  ((float4*)(out + (size_t)t * D_))[tid] = v;
}

// ---------------------------------------------------------------------------
extern "C" void kernel_launch(void* const* d_in, const int* in_sizes, int n_in,
                              void* d_out, int out_size, void* d_ws, size_t ws_size,
                              hipStream_t stream) {
  const float* x    = (const float*)d_in[0];
  const float* g1   = (const float*)d_in[1];
  const float* wqkv = (const float*)d_in[2];
  const float* wo   = (const float*)d_in[3];
  const float* g2   = (const float*)d_in[4];
  const float* wr   = (const float*)d_in[5];
  const float* w1   = (const float*)d_in[6];
  const float* w2   = (const float*)d_in[7];
  float* out = (float*)d_out;
  char* ws = (char*)d_ws;
  const size_t MB = 1ull << 20;

  // Phase-aliased workspace layout (~233 MB):
  u16*   y1hh  = (u16*)  (ws + 0);          // 8MB  fp16-hi of rmsnorm1 out
  u16*   y1hl  = (u16*)  (ws + 8 * MB);     // 8MB  fp16-lo
  u16*   ahh   = (u16*)  (ws + 16 * MB);    // 8MB  attn out fp16-hi
  u16*   ahl   = (u16*)  (ws + 24 * MB);    // 8MB  attn out fp16-lo
  u16*   hbf   = (u16*)  (ws + 0);          // 40MB MoE hidden (aliases the above)
  float* qkv   = (float*)(ws + 40 * MB);    // 48MB, dead after rope/v split
  u16*   xe    = (u16*)  (ws + 40 * MB);    // 20MB, aliases qkv (MoE time)
  float* x2    = (float*)(ws + 88 * MB);    // 16MB
  float* y2    = (float*)(ws + 104 * MB);   // 16MB (fp32 for router!)
  u16*   y2b   = (u16*)  (ws + 120 * MB);   // 8MB
  u16*   w1t   = (u16*)  (ws + 128 * MB);   // 32MB  [E][FFN][D] bf16
  u16*   w2t   = (u16*)  (ws + 160 * MB);   // 32MB  [E][D][FFN] bf16
  float* ye    = (float*)(ws + 192 * MB);   // 40MB (MoE time)
  u16*   wqh   = (u16*)  (ws + 192 * MB);   // 6MB  w_qkv^T fp16-hi (dead before rope)
  u16*   wql   = (u16*)  (ws + 198 * MB);   // 6MB  fp16-lo
  u16*   khi   = (u16*)  (ws + 192 * MB);   // 8MB  (after QKV gemm)
  u16*   klo   = (u16*)  (ws + 200 * MB);   // 8MB
  u16*   vthi  = (u16*)  (ws + 208 * MB);   // 8MB
  u16*   vtlo  = (u16*)  (ws + 216 * MB);   // 8MB
  u16*   woh   = (u16*)  (ws + 224 * MB);   // 2MB  w_o^T fp16-hi (dead before MoE ye)
  u16*   wol   = (u16*)  (ws + 226 * MB);   // 2MB
  int*   cnt   = (int*)  (ws + 232 * MB);
  int*   tok_e = cnt + 16;                  // 2*T
  float* tok_g = (float*)(tok_e + 2 * T_);  // 2*T
  int*   tok_p = (int*)  (tok_g + 2 * T_);  // 2*T
  int*   etok  = tok_p + 2 * T_;            // E*CAP

  init_k<<<1, 64, 0, stream>>>(cnt);
  transpose_bf_k<<<dim3(FFN_/32, D_/32, E_), 256, 0, stream>>>(w1, w1t, D_, FFN_);
  transpose_bf_k<<<dim3(D_/32, FFN_/32, E_), 256, 0, stream>>>(w2, w2t, FFN_, D_);
  // w_qkv (Dx3D) -> [3D][D] fp16 hi/lo; w_o (DxD) -> [D][D] fp16 hi/lo
  wsplit_t_k<<<dim3(3*D_/32, D_/32), 256, 0, stream>>>(wqkv, wqh, wql, D_, 3*D_);
  wsplit_t_k<<<dim3(D_/32, D_/32), 256, 0, stream>>>(wo, woh, wol, D_, D_);

  // x -> rmsnorm -> y1 (fp16 hi/lo only)
  rmsnorm_k<<<T_, 256, 0, stream>>>(x, g1, (float*)nullptr, (u16*)nullptr, y1hh, y1hl);
  // qkv = y1 @ w_qkv via split-fp16 MFMA (fp32 out)
  gemm_split<false><<<dim3(3 * D_ / 128, T_ / 128), 256, 0, stream>>>(
      y1hh, y1hl, wqh, wql, nullptr, qkv, D_, D_, D_, 3 * D_);
  // RoPE + split q,k (q pre-scaled by 1/8); transpose + split v
  ropesplit_k<<<T_ * H_ * 32 / 256, 256, 0, stream>>>(qkv, y1hh /*reuse? no*/, y1hl, khi, klo);
  // NOTE: q split must NOT alias y1 (still also unused now) — use dedicated:
  // (y1hh/y1hl are dead after the QKV gemm, so reusing them for qhi/qlo is safe)
  vsplit_k<<<dim3(S_ / 64, B_ * H_), 256, 0, stream>>>(qkv, vthi, vtlo);
  // split-bf16 MFMA flash attention -> fp16 hi/lo [B,S,D]
  attn_mfma_k<<<dim3(S_ / 64, B_ * H_), 256, 0, stream>>>(
      y1hh, y1hl, khi, klo, vthi, vtlo, ahh, ahl);
  // x2 = attn @ w_o + x via split-fp16 MFMA
  gemm_split<true><<<dim3(D_ / 128, T_ / 128), 256, 0, stream>>>(
      ahh, ahl, woh, wol, x, x2, D_, D_, D_, D_);
  // x2 -> rmsnorm -> y2 (fp32) + y2b (bf16)
  rmsnorm_k<<<T_, 256, 0, stream>>>(x2, g2, y2, y2b, (u16*)nullptr, (u16*)nullptr);
  // router (fp32 logits, top-2, capacity assignment)
  router_k<<<T_ / 4, 256, 0, stream>>>(y2, wr, cnt, tok_e, tok_g, tok_p, etok);
  // gather per-expert token rows (bf16)
  gather_k<<<dim3(CAP_, E_), 256, 0, stream>>>(y2b, etok, cnt, xe);
  // h = relu(xe @ w1) (bf16 out), batched over experts
  gemm_bt<u16, true><<<dim3(FFN_/128, CAP_/128, E_), 256, 0, stream>>>(
      xe, w1t, hbf, CAP_, FFN_, D_, D_, D_, FFN_,
      (long)CAP_ * D_, (long)FFN_ * D_, (long)CAP_ * FFN_);
  // ye = h @ w2 (fp32 out)
  gemm_bt<float, false><<<dim3(D_/128, CAP_/128, E_), 256, 0, stream>>>(
      hbf, w2t, ye, CAP_, D_, FFN_, FFN_, FFN_, D_,
      (long)CAP_ * FFN_, (long)D_ * FFN_, (long)CAP_ * D_);
  // out = x2 + sum_r gate_r * ye[...]
  combine_k<<<T_, 256, 0, stream>>>(x2, ye, tok_e, tok_g, tok_p, out);
}

// Round 4
// 793.832 us; speedup vs baseline: 3.0668x; 1.0621x over previous
//
#include <hip/hip_runtime.h>
#include <math.h>

// ---------------------------------------------------------------------------
// Fused transformer block on MI355X.
// Precision: all pre-router math is fp32-equivalent (split-fp16/bf16 MFMA),
// post-routing MoE GEMMs plain bf16 MFMA. See R1-R3 notes.
// R4: attention split-K (2 chunks for qt>=16) + combine pass; global_load_lds
// width-16 staging in gemm_split / gemm_bt (m97 pattern).
// ---------------------------------------------------------------------------

#define B_   2
#define S_   2048
#define D_   1024
#define H_   16
#define HD_  64
#define FFN_ 2048
#define E_   8
#define CAP_ 1280
#define T_   (B_*S_)

typedef unsigned short u16;
typedef __attribute__((ext_vector_type(8))) short     short8;    // MFMA bf16x8 operand
typedef __attribute__((ext_vector_type(8))) _Float16  half8;     // MFMA f16x8 operand
typedef __attribute__((ext_vector_type(8))) unsigned short ushort8v;
typedef __attribute__((ext_vector_type(4))) float     f32x4;

__device__ __forceinline__ u16 f2bf(float f) {
  unsigned u = __float_as_uint(f);
  return (u16)((u + 0x7fffu + ((u >> 16) & 1u)) >> 16);   // RNE
}
__device__ __forceinline__ float bf2f(u16 h) {
  return __uint_as_float(((unsigned)h) << 16);
}
__device__ __forceinline__ u16 f2h(float f) {
  _Float16 h = (_Float16)f;
  return __builtin_bit_cast(u16, h);
}
__device__ __forceinline__ float h2f(u16 b) {
  return (float)__builtin_bit_cast(_Float16, b);
}

__device__ __forceinline__ void cstore(float* p, float v) { *p = v; }
__device__ __forceinline__ void cstore(u16* p, float v)   { *p = f2bf(v); }

// global -> LDS direct DMA, 16B per lane. LDS dest must be lane-linear
// (base + lane*16) within the wave.
__device__ __forceinline__ void glds16(const u16* g, u16* l) {
  __builtin_amdgcn_global_load_lds(
      (const __attribute__((address_space(1))) unsigned int*)g,
      (__attribute__((address_space(3))) unsigned int*)l, 16, 0, 0);
}

// --------------------------- init: zero expert counters --------------------
__global__ void init_k(int* cnt) {
  if (threadIdx.x < 16) cnt[threadIdx.x] = 0;
}

// --------------------------- RMSNorm (fp32 in; fp32/bf16/fp16-split out) ---
__global__ __launch_bounds__(256) void rmsnorm_k(const float* __restrict__ x,
                                                 const float* __restrict__ g,
                                                 float* __restrict__ of,
                                                 u16*   __restrict__ ob,
                                                 u16*   __restrict__ ohh,
                                                 u16*   __restrict__ ohl) {
  const int t = blockIdx.x, tid = threadIdx.x;
  const float4 xv = ((const float4*)(x + (size_t)t * D_))[tid];
  float ss = xv.x*xv.x + xv.y*xv.y + xv.z*xv.z + xv.w*xv.w;
  #pragma unroll
  for (int off = 32; off; off >>= 1) ss += __shfl_down(ss, off);
  __shared__ float wsum[4];
  if ((tid & 63) == 0) wsum[tid >> 6] = ss;
  __syncthreads();
  const float tot = wsum[0] + wsum[1] + wsum[2] + wsum[3];
  const float rms = 1.0f / sqrtf(tot * (1.0f / D_) + 1e-6f);
  const float4 gv = ((const float4*)g)[tid];
  float4 o;
  o.x = gv.x * xv.x * rms;
  o.y = gv.y * xv.y * rms;
  o.z = gv.z * xv.z * rms;
  o.w = gv.w * xv.w * rms;
  if (of) ((float4*)(of + (size_t)t * D_))[tid] = o;
  if (ob) {
    ushort4 h;
    h.x = f2bf(o.x); h.y = f2bf(o.y); h.z = f2bf(o.z); h.w = f2bf(o.w);
    ((ushort4*)(ob + (size_t)t * D_))[tid] = h;
  }
  if (ohh) {
    ushort4 hh, hl;
    hh.x = f2h(o.x); hl.x = f2h(o.x - h2f(hh.x));
    hh.y = f2h(o.y); hl.y = f2h(o.y - h2f(hh.y));
    hh.z = f2h(o.z); hl.z = f2h(o.z - h2f(hh.z));
    hh.w = f2h(o.w); hl.w = f2h(o.w - h2f(hh.w));
    ((ushort4*)(ohh + (size_t)t * D_))[tid] = hh;
    ((ushort4*)(ohl + (size_t)t * D_))[tid] = hl;
  }
}

// --------------------------- split-fp16 MFMA GEMM: C = (A)(Bt)^T (+resid) --
// 128x128 tile, BK=32, 4 waves 2x2, 3 MFMA products (hh, hl, lh) per tile.
// Staging via global_load_lds width=16.
template<bool RESID>
__global__ __launch_bounds__(256) void gemm_split(const u16* __restrict__ Ah,
                                                  const u16* __restrict__ Al,
                                                  const u16* __restrict__ Bh,
                                                  const u16* __restrict__ Bl,
                                                  const float* __restrict__ resid,
                                                  float* __restrict__ C,
                                                  int K, int lda, int ldb, int ldc) {
  __shared__ u16 AsH[128 * 32], AsL[128 * 32];
  __shared__ u16 BsH[128 * 32], BsL[128 * 32];
  const int tid = threadIdx.x;
  const int bm = blockIdx.y, bn = blockIdx.x;
  const int lane = tid & 63, wave = tid >> 6;
  const int wy = wave >> 1, wx = wave & 1;
  const int l15 = lane & 15, lq = lane >> 4;
  f32x4 acc[4][4];
  #pragma unroll
  for (int i = 0; i < 4; ++i)
    #pragma unroll
    for (int j = 0; j < 4; ++j)
      #pragma unroll
      for (int r = 0; r < 4; ++r) acc[i][j][r] = 0.0f;
  // staging map: chunk q = wave*2+c covers rows [q*16, q*16+16), lane covers
  // row q*16+(lane>>2), k-col (lane&3)*8; LDS offset = q*512 + lane*8 (u16).
  const int srow = lane >> 2, skc = (lane & 3) * 8;
  size_t ga[2], gb[2];
  int ldsoff[2];
  #pragma unroll
  for (int c = 0; c < 2; ++c) {
    const int q = wave * 2 + c;
    ga[c] = (size_t)(bm * 128 + q * 16 + srow) * lda + skc;
    gb[c] = (size_t)(bn * 128 + q * 16 + srow) * ldb + skc;
    ldsoff[c] = q * 512 + lane * 8;
  }

  for (int kt = 0; kt < K; kt += 32) {
    __syncthreads();
    #pragma unroll
    for (int c = 0; c < 2; ++c) {
      glds16(Ah + ga[c] + kt, &AsH[ldsoff[c]]);
      glds16(Al + ga[c] + kt, &AsL[ldsoff[c]]);
      glds16(Bh + gb[c] + kt, &BsH[ldsoff[c]]);
      glds16(Bl + gb[c] + kt, &BsL[ldsoff[c]]);
    }
    __syncthreads();
    half8 ah[4], al[4], bh[4], bl[4];
    #pragma unroll
    for (int i = 0; i < 4; ++i) {
      const int row = (wy * 64 + i * 16 + l15) * 32 + lq * 8;
      ah[i] = *(const half8*)&AsH[row];
      al[i] = *(const half8*)&AsL[row];
    }
    #pragma unroll
    for (int j = 0; j < 4; ++j) {
      const int row = (wx * 64 + j * 16 + l15) * 32 + lq * 8;
      bh[j] = *(const half8*)&BsH[row];
      bl[j] = *(const half8*)&BsL[row];
    }
    #pragma unroll
    for (int i = 0; i < 4; ++i)
      #pragma unroll
      for (int j = 0; j < 4; ++j) {
        acc[i][j] = __builtin_amdgcn_mfma_f32_16x16x32_f16(ah[i], bh[j], acc[i][j], 0, 0, 0);
        acc[i][j] = __builtin_amdgcn_mfma_f32_16x16x32_f16(ah[i], bl[j], acc[i][j], 0, 0, 0);
        acc[i][j] = __builtin_amdgcn_mfma_f32_16x16x32_f16(al[i], bh[j], acc[i][j], 0, 0, 0);
      }
  }
  #pragma unroll
  for (int i = 0; i < 4; ++i)
    #pragma unroll
    for (int j = 0; j < 4; ++j)
      #pragma unroll
      for (int r = 0; r < 4; ++r) {
        const int row = bm * 128 + wy * 64 + i * 16 + lq * 4 + r;
        const int col = bn * 128 + wx * 64 + j * 16 + l15;
        float v = acc[i][j][r];
        if (RESID) v += resid[(size_t)row * ldc + col];
        C[(size_t)row * ldc + col] = v;
      }
}

// --------------------------- weight transpose + fp16 split -----------------
__global__ __launch_bounds__(256) void wsplit_t_k(const float* __restrict__ src,
                                                  u16* __restrict__ dh,
                                                  u16* __restrict__ dl,
                                                  int R, int C) {
  __shared__ float tile[32][33];
  const int tid = threadIdx.x;
  const int r0 = blockIdx.y * 32, c0 = blockIdx.x * 32;
  const int tx = tid & 31, ty = tid >> 5;
  #pragma unroll
  for (int i = 0; i < 4; ++i)
    tile[ty + i * 8][tx] = src[(size_t)(r0 + ty + i * 8) * C + c0 + tx];
  __syncthreads();
  #pragma unroll
  for (int i = 0; i < 4; ++i) {
    const float v = tile[tx][ty + i * 8];
    const u16 hh = f2h(v);
    const size_t o = (size_t)(c0 + ty + i * 8) * R + r0 + tx;
    dh[o] = hh;
    dl[o] = f2h(v - h2f(hh));
  }
}

// --------------------------- RoPE + split q,k -> bf16 hi/lo ----------------
__global__ __launch_bounds__(256) void ropesplit_k(const float* __restrict__ qkv,
                                                   u16* __restrict__ qhi, u16* __restrict__ qlo,
                                                   u16* __restrict__ khi, u16* __restrict__ klo) {
  const int i = blockIdx.x * 256 + threadIdx.x;   // over T_*H_*32
  const int j = i & 31;
  const int h = (i >> 5) & 15;
  const int t = i >> 9;
  const int s = t & (S_ - 1);
  const int b = t >> 11;
  const int bh = b * 16 + h;
  const float theta = (float)pow(10000.0, -(double)j / 32.0);
  const float fr = (float)s * theta;
  const float c = cosf(fr), sn = sinf(fr);
  const float2 q = *(const float2*)(qkv + (size_t)t * 3072 + h * 64 + 2 * j);
  const float2 k = *(const float2*)(qkv + (size_t)t * 3072 + 1024 + h * 64 + 2 * j);
  const float q0 = (q.x * c - q.y * sn) * 0.125f;
  const float q1 = (q.x * sn + q.y * c) * 0.125f;
  const float k0 = k.x * c - k.y * sn;
  const float k1 = k.x * sn + k.y * c;
  const size_t o = ((size_t)bh * S_ + s) * 32 + j;   // uint (2xu16) index
  const u16 qh0 = f2bf(q0), qh1 = f2bf(q1);
  const u16 kh0 = f2bf(k0), kh1 = f2bf(k1);
  ((unsigned*)qhi)[o] = (unsigned)qh0 | ((unsigned)qh1 << 16);
  ((unsigned*)khi)[o] = (unsigned)kh0 | ((unsigned)kh1 << 16);
  const u16 ql0 = f2bf(q0 - bf2f(qh0)), ql1 = f2bf(q1 - bf2f(qh1));
  const u16 kl0 = f2bf(k0 - bf2f(kh0)), kl1 = f2bf(k1 - bf2f(kh1));
  ((unsigned*)qlo)[o] = (unsigned)ql0 | ((unsigned)ql1 << 16);
  ((unsigned*)klo)[o] = (unsigned)kl0 | ((unsigned)kl1 << 16);
}

// --------------------------- V: transpose + split -> [bh][d][s] bf16 -------
__global__ __launch_bounds__(256) void vsplit_k(const float* __restrict__ qkv,
                                                u16* __restrict__ vthi,
                                                u16* __restrict__ vtlo) {
  __shared__ float tile[64][65];
  const int st = blockIdx.x, bh = blockIdx.y;
  const int b = bh >> 4, h = bh & 15;
  const int tid = threadIdx.x;
  const int c = tid & 63, r4 = tid >> 6;
  #pragma unroll
  for (int i = 0; i < 16; ++i) {
    const int r = i * 4 + r4;
    tile[r][c] = qkv[(size_t)(b * S_ + st * 64 + r) * 3072 + 2048 + h * 64 + c];
  }
  __syncthreads();
  #pragma unroll
  for (int i = 0; i < 16; ++i) {
    const int d = i * 4 + r4;
    const float v = tile[c][d];
    const u16 hi = f2bf(v);
    const size_t o = ((size_t)bh * 64 + d) * S_ + st * 64 + c;
    vthi[o] = hi;
    vtlo[o] = f2bf(v - bf2f(hi));
  }
}

// --------------------------- split-bf16 MFMA flash attention (split-K) -----
// blockIdx.x in [0,48): i<32 -> heavy half-blocks (qt=31-(i>>1), chunk=i&1,
// partial output); i>=32 -> light full blocks (qt=47-i, direct output).
__global__ __launch_bounds__(256) void attn_mfma_k(const u16* __restrict__ qhi,
                                                   const u16* __restrict__ qlo,
                                                   const u16* __restrict__ khi,
                                                   const u16* __restrict__ klo,
                                                   const u16* __restrict__ vthi,
                                                   const u16* __restrict__ vtlo,
                                                   u16* __restrict__ ahh,
                                                   u16* __restrict__ ahl,
                                                   float* __restrict__ PO,
                                                   float* __restrict__ Pm,
                                                   float* __restrict__ Pl2) {
  __shared__ u16 Kh[64 * 68], Kl[64 * 68];   // [key][dim]
  __shared__ u16 Vh[64 * 68], Vl[64 * 68];   // [dim][key]
  __shared__ u16 Ph[4][16 * 68], Pl[4][16 * 68];  // per-wave P round-trip
  const int tid = threadIdx.x, lane = tid & 63, wave = tid >> 6;
  const int bi = blockIdx.x;
  int qt, k0, k1, chunk;
  bool partial;
  if (bi < 32) {
    qt = 31 - (bi >> 1); chunk = bi & 1;
    const int nk = qt + 1, cut = nk >> 1;
    k0 = chunk ? cut : 0;
    k1 = chunk ? nk : cut;
    partial = true;
  } else {
    qt = 47 - bi; chunk = 0; k0 = 0; k1 = qt + 1; partial = false;
  }
  const int bh = blockIdx.y;
  const int l15 = lane & 15, lq = lane >> 4;
  const size_t hb = (size_t)bh * S_ * 64;
  const int qrow = qt * 64 + wave * 16 + l15;
  short8 qh[2], ql[2];
  qh[0] = *(const short8*)(qhi + hb + (size_t)qrow * 64 + lq * 8);
  qh[1] = *(const short8*)(qhi + hb + (size_t)qrow * 64 + 32 + lq * 8);
  ql[0] = *(const short8*)(qlo + hb + (size_t)qrow * 64 + lq * 8);
  ql[1] = *(const short8*)(qlo + hb + (size_t)qrow * 64 + 32 + lq * 8);
  f32x4 O[4];
  float m_i[4], l_i[4];
  #pragma unroll
  for (int n = 0; n < 4; ++n)
    #pragma unroll
    for (int r = 0; r < 4; ++r) O[n][r] = 0.0f;
  #pragma unroll
  for (int r = 0; r < 4; ++r) { m_i[r] = -__builtin_inff(); l_i[r] = 0.0f; }

  for (int kt = k0; kt < k1; ++kt) {
    __syncthreads();
    #pragma unroll
    for (int it = 0; it < 2; ++it) {
      const int idx = it * 256 + tid;
      const int row = idx >> 3, c8 = (idx & 7) * 8;
      const size_t koff = hb + (size_t)(kt * 64 + row) * 64 + c8;
      *(ushort8v*)&Kh[row * 68 + c8] = *(const ushort8v*)(khi + koff);
      *(ushort8v*)&Kl[row * 68 + c8] = *(const ushort8v*)(klo + koff);
      const size_t voff = ((size_t)bh * 64 + row) * S_ + kt * 64 + c8;
      *(ushort8v*)&Vh[row * 68 + c8] = *(const ushort8v*)(vthi + voff);
      *(ushort8v*)&Vl[row * 68 + c8] = *(const ushort8v*)(vtlo + voff);
    }
    __syncthreads();
    // ---- S = Q K^T (3-product split) ----
    f32x4 sc[4];
    #pragma unroll
    for (int n = 0; n < 4; ++n)
      #pragma unroll
      for (int r = 0; r < 4; ++r) sc[n][r] = 0.0f;
    #pragma unroll
    for (int n = 0; n < 4; ++n) {
      const int krow = (n * 16 + l15) * 68 + lq * 8;
      const short8 kb0 = *(const short8*)&Kh[krow];
      const short8 kb1 = *(const short8*)&Kh[krow + 32];
      const short8 kl0 = *(const short8*)&Kl[krow];
      const short8 kl1 = *(const short8*)&Kl[krow + 32];
      sc[n] = __builtin_amdgcn_mfma_f32_16x16x32_bf16(qh[0], kb0, sc[n], 0, 0, 0);
      sc[n] = __builtin_amdgcn_mfma_f32_16x16x32_bf16(qh[1], kb1, sc[n], 0, 0, 0);
      sc[n] = __builtin_amdgcn_mfma_f32_16x16x32_bf16(qh[0], kl0, sc[n], 0, 0, 0);
      sc[n] = __builtin_amdgcn_mfma_f32_16x16x32_bf16(qh[1], kl1, sc[n], 0, 0, 0);
      sc[n] = __builtin_amdgcn_mfma_f32_16x16x32_bf16(ql[0], kb0, sc[n], 0, 0, 0);
      sc[n] = __builtin_amdgcn_mfma_f32_16x16x32_bf16(ql[1], kb1, sc[n], 0, 0, 0);
    }
    // ---- causal mask on the diagonal tile ----
    if (kt == qt) {
      #pragma unroll
      for (int n = 0; n < 4; ++n)
        #pragma unroll
        for (int r = 0; r < 4; ++r)
          if (n * 16 + l15 > wave * 16 + lq * 4 + r) sc[n][r] = -__builtin_inff();
    }
    // ---- online softmax (rows live across 16 lanes l15, per reg r) ----
    float al[4];
    #pragma unroll
    for (int r = 0; r < 4; ++r) {
      float mx = fmaxf(fmaxf(sc[0][r], sc[1][r]), fmaxf(sc[2][r], sc[3][r]));
      mx = fmaxf(mx, __shfl_xor(mx, 1));
      mx = fmaxf(mx, __shfl_xor(mx, 2));
      mx = fmaxf(mx, __shfl_xor(mx, 4));
      mx = fmaxf(mx, __shfl_xor(mx, 8));
      const float mn = fmaxf(m_i[r], mx);
      al[r] = __expf(m_i[r] - mn);
      m_i[r] = mn;
    }
    f32x4 p[4];
    #pragma unroll
    for (int n = 0; n < 4; ++n)
      #pragma unroll
      for (int r = 0; r < 4; ++r) p[n][r] = __expf(sc[n][r] - m_i[r]);
    #pragma unroll
    for (int r = 0; r < 4; ++r) {
      float rs = p[0][r] + p[1][r] + p[2][r] + p[3][r];
      rs += __shfl_xor(rs, 1);
      rs += __shfl_xor(rs, 2);
      rs += __shfl_xor(rs, 4);
      rs += __shfl_xor(rs, 8);
      l_i[r] = l_i[r] * al[r] + rs;
      O[0][r] *= al[r]; O[1][r] *= al[r]; O[2][r] *= al[r]; O[3][r] *= al[r];
    }
    // ---- P: C-layout regs -> LDS in A-layout, split hi/lo ----
    #pragma unroll
    for (int n = 0; n < 4; ++n)
      #pragma unroll
      for (int r = 0; r < 4; ++r) {
        const float v = p[n][r];
        const u16 hi = f2bf(v);
        const int a = (lq * 4 + r) * 68 + n * 16 + l15;
        Ph[wave][a] = hi;
        Pl[wave][a] = f2bf(v - bf2f(hi));
      }
    asm volatile("s_waitcnt lgkmcnt(0)" ::: "memory");
    short8 pah[2], pal[2];
    pah[0] = *(const short8*)&Ph[wave][l15 * 68 + lq * 8];
    pah[1] = *(const short8*)&Ph[wave][l15 * 68 + 32 + lq * 8];
    pal[0] = *(const short8*)&Pl[wave][l15 * 68 + lq * 8];
    pal[1] = *(const short8*)&Pl[wave][l15 * 68 + 32 + lq * 8];
    // ---- O += P V (3-product split); V in LDS is [dim][key] = B^T layout --
    #pragma unroll
    for (int n = 0; n < 4; ++n) {
      const int vrow = (n * 16 + l15) * 68 + lq * 8;
      const short8 vb0 = *(const short8*)&Vh[vrow];
      const short8 vb1 = *(const short8*)&Vh[vrow + 32];
      const short8 vl0 = *(const short8*)&Vl[vrow];
      const short8 vl1 = *(const short8*)&Vl[vrow + 32];
      O[n] = __builtin_amdgcn_mfma_f32_16x16x32_bf16(pah[0], vb0, O[n], 0, 0, 0);
      O[n] = __builtin_amdgcn_mfma_f32_16x16x32_bf16(pah[1], vb1, O[n], 0, 0, 0);
      O[n] = __builtin_amdgcn_mfma_f32_16x16x32_bf16(pah[0], vl0, O[n], 0, 0, 0);
      O[n] = __builtin_amdgcn_mfma_f32_16x16x32_bf16(pah[1], vl1, O[n], 0, 0, 0);
      O[n] = __builtin_amdgcn_mfma_f32_16x16x32_bf16(pal[0], vb0, O[n], 0, 0, 0);
      O[n] = __builtin_amdgcn_mfma_f32_16x16x32_bf16(pal[1], vb1, O[n], 0, 0, 0);
    }
  }
  const int b = bh >> 4, h = bh & 15;
  if (!partial) {
    #pragma unroll
    for (int r = 0; r < 4; ++r) {
      const float inv = 1.0f / l_i[r];
      const int row = qt * 64 + wave * 16 + lq * 4 + r;
      const size_t base = (size_t)(b * S_ + row) * D_ + h * 64 + l15;
      #pragma unroll
      for (int n = 0; n < 4; ++n) {
        const float o = O[n][r] * inv;
        const u16 hh = f2h(o);
        ahh[base + n * 16] = hh;
        ahl[base + n * 16] = f2h(o - h2f(hh));
      }
    }
  } else {
    // unnormalized partials; rows are >= 1024 since qt >= 16
    #pragma unroll
    for (int r = 0; r < 4; ++r) {
      const int prow = qt * 64 + wave * 16 + lq * 4 + r - 1024;
      const size_t idx = (size_t)(chunk * 32 + bh) * 1024 + prow;
      float* po = PO + idx * 64;
      #pragma unroll
      for (int n = 0; n < 4; ++n) po[n * 16 + l15] = O[n][r];
      if (l15 == 0) { Pm[idx] = m_i[r]; Pl2[idx] = l_i[r]; }
    }
  }
}

// --------------------------- combine split-K attention partials ------------
// grid (16 row-tiles, 32 bh), 256 thr: thread -> (row = tid>>2, 16 dims).
__global__ __launch_bounds__(256) void attn_combine_k(const float* __restrict__ PO,
                                                      const float* __restrict__ Pm,
                                                      const float* __restrict__ Pl2,
                                                      u16* __restrict__ ahh,
                                                      u16* __restrict__ ahl) {
  const int tid = threadIdx.x;
  const int bh = blockIdx.y, b = bh >> 4, h = bh & 15;
  const int prow = blockIdx.x * 64 + (tid >> 2);
  const int d0 = (tid & 3) * 16;
  const size_t i0 = (size_t)bh * 1024 + prow;
  const size_t i1 = (size_t)(32 + bh) * 1024 + prow;
  const float m0 = Pm[i0], m1 = Pm[i1];
  const float M = fmaxf(m0, m1);
  const float w0 = __expf(m0 - M), w1 = __expf(m1 - M);
  const float inv = 1.0f / (w0 * Pl2[i0] + w1 * Pl2[i1]);
  const int row = 1024 + prow;
  const size_t ob = (size_t)(b * S_ + row) * D_ + h * 64 + d0;
  #pragma unroll
  for (int q4 = 0; q4 < 4; ++q4) {
    const float4 o0 = *(const float4*)(PO + i0 * 64 + d0 + q4 * 4);
    const float4 o1 = *(const float4*)(PO + i1 * 64 + d0 + q4 * 4);
    float v[4];
    v[0] = (w0 * o0.x + w1 * o1.x) * inv;
    v[1] = (w0 * o0.y + w1 * o1.y) * inv;
    v[2] = (w0 * o0.z + w1 * o1.z) * inv;
    v[3] = (w0 * o0.w + w1 * o1.w) * inv;
    ushort4 hh, hl;
    u16* ph = (u16*)&hh;
    u16* pl = (u16*)&hl;
    #pragma unroll
    for (int z = 0; z < 4; ++z) {
      ph[z] = f2h(v[z]);
      pl[z] = f2h(v[z] - h2f(ph[z]));
    }
    *(ushort4*)(ahh + ob + q4 * 4) = hh;
    *(ushort4*)(ahl + ob + q4 * 4) = hl;
  }
}

// --------------------------- router: logits + top2 + capacity assign -------
__global__ __launch_bounds__(256) void router_k(const float* __restrict__ y2,
                                                const float* __restrict__ wr,
                                                int*   __restrict__ cnt,
                                                int*   __restrict__ tok_e,
                                                float* __restrict__ tok_g,
                                                int*   __restrict__ tok_p,
                                                int*   __restrict__ etok) {
  const int wave = threadIdx.x >> 6, lane = threadIdx.x & 63;
  const int t = blockIdx.x * 4 + wave;
  const float* xr = y2 + (size_t)t * D_;
  float acc[8];
  #pragma unroll
  for (int e = 0; e < 8; ++e) acc[e] = 0.0f;
  for (int c = 0; c < 16; ++c) {
    const float xv = xr[c * 64 + lane];
    const float* w = wr + (size_t)(c * 64 + lane) * 8;
    #pragma unroll
    for (int e = 0; e < 8; ++e) acc[e] = fmaf(xv, w[e], acc[e]);
  }
  #pragma unroll
  for (int off = 32; off; off >>= 1)
    #pragma unroll
    for (int e = 0; e < 8; ++e) acc[e] += __shfl_down(acc[e], off);
  if (lane == 0) {
    float mx = acc[0];
    #pragma unroll
    for (int e = 1; e < 8; ++e) mx = fmaxf(mx, acc[e]);
    float ex[8], sum = 0.0f;
    #pragma unroll
    for (int e = 0; e < 8; ++e) { ex[e] = expf(acc[e] - mx); sum += ex[e]; }
    int e1 = 0;
    #pragma unroll
    for (int e = 1; e < 8; ++e) if (acc[e] > acc[e1]) e1 = e;
    int e2 = (e1 == 0) ? 1 : 0;
    #pragma unroll
    for (int e = 0; e < 8; ++e) if (e != e1 && acc[e] > acc[e2]) e2 = e;
    const float g1v = ex[e1] / sum, g2v = ex[e2] / sum;
    int p1 = atomicAdd(&cnt[e1], 1);
    int p2 = atomicAdd(&cnt[e2], 1);
    if (p1 < CAP_) etok[e1 * CAP_ + p1] = t; else p1 = -1;
    if (p2 < CAP_) etok[e2 * CAP_ + p2] = t; else p2 = -1;
    tok_e[2*t] = e1;   tok_e[2*t+1] = e2;
    tok_g[2*t] = g1v;  tok_g[2*t+1] = g2v;
    tok_p[2*t] = p1;   tok_p[2*t+1] = p2;
  }
}

// --------------------------- gather tokens per expert (bf16) ---------------
__global__ __launch_bounds__(256) void gather_k(const u16* __restrict__ y2b,
                                                const int* __restrict__ etok,
                                                const int* __restrict__ cnt,
                                                u16* __restrict__ xe) {
  const int e = blockIdx.y, pos = blockIdx.x, tid = threadIdx.x;
  const int n = min(cnt[e], CAP_);
  ushort4* dst = (ushort4*)(xe + (size_t)(e * CAP_ + pos) * D_) + tid;
  if (pos < n) {
    const int t = etok[e * CAP_ + pos];
    *dst = ((const ushort4*)(y2b + (size_t)t * D_))[tid];
  } else {
    *dst = make_ushort4(0, 0, 0, 0);
  }
}

// --------------------------- bf16 MFMA GEMM: C = A * Bt^T ------------------
// Staging via global_load_lds width=16.
template<typename OT, bool RELU>
__global__ __launch_bounds__(256) void gemm_bt(const u16* __restrict__ A,
                                               const u16* __restrict__ Bt,
                                               OT* __restrict__ C,
                                               int M, int N, int K,
                                               int lda, int ldb, int ldc,
                                               long sAz, long sBz, long sCz) {
  __shared__ u16 As[128 * 32];
  __shared__ u16 Bs[128 * 32];
  const int tid = threadIdx.x;
  A  += (size_t)blockIdx.z * sAz;
  Bt += (size_t)blockIdx.z * sBz;
  C  += (size_t)blockIdx.z * sCz;
  const int bm = blockIdx.y, bn = blockIdx.x;
  const int lane = tid & 63, wave = tid >> 6;
  const int wy = wave >> 1, wx = wave & 1;
  const int l15 = lane & 15, lq = lane >> 4;
  f32x4 acc[4][4];
  #pragma unroll
  for (int i = 0; i < 4; ++i)
    #pragma unroll
    for (int j = 0; j < 4; ++j)
      #pragma unroll
      for (int r = 0; r < 4; ++r) acc[i][j][r] = 0.0f;
  const int srow = lane >> 2, skc = (lane & 3) * 8;
  size_t ga[2], gb[2];
  int ldsoff[2];
  #pragma unroll
  for (int c = 0; c < 2; ++c) {
    const int q = wave * 2 + c;
    ga[c] = (size_t)(bm * 128 + q * 16 + srow) * lda + skc;
    gb[c] = (size_t)(bn * 128 + q * 16 + srow) * ldb + skc;
    ldsoff[c] = q * 512 + lane * 8;
  }

  for (int kt = 0; kt < K; kt += 32) {
    __syncthreads();
    #pragma unroll
    for (int c = 0; c < 2; ++c) {
      glds16(A  + ga[c] + kt, &As[ldsoff[c]]);
      glds16(Bt + gb[c] + kt, &Bs[ldsoff[c]]);
    }
    __syncthreads();
    short8 a[4], b[4];
    #pragma unroll
    for (int i = 0; i < 4; ++i)
      a[i] = *(const short8*)&As[(wy * 64 + i * 16 + l15) * 32 + lq * 8];
    #pragma unroll
    for (int j = 0; j < 4; ++j)
      b[j] = *(const short8*)&Bs[(wx * 64 + j * 16 + l15) * 32 + lq * 8];
    #pragma unroll
    for (int i = 0; i < 4; ++i)
      #pragma unroll
      for (int j = 0; j < 4; ++j)
        acc[i][j] = __builtin_amdgcn_mfma_f32_16x16x32_bf16(a[i], b[j], acc[i][j], 0, 0, 0);
  }
  #pragma unroll
  for (int i = 0; i < 4; ++i)
    #pragma unroll
    for (int j = 0; j < 4; ++j)
      #pragma unroll
      for (int r = 0; r < 4; ++r) {
        const int row = bm * 128 + wy * 64 + i * 16 + lq * 4 + r;
        const int col = bn * 128 + wx * 64 + j * 16 + l15;
        float v = acc[i][j][r];
        if (RELU) v = fmaxf(v, 0.0f);
        cstore(C + (size_t)row * ldc + col, v);
      }
}

// --------------------------- weight transpose fp32 -> bf16^T ---------------
__global__ __launch_bounds__(256) void transpose_bf_k(const float* __restrict__ src,
                                                      u16* __restrict__ dst,
                                                      int R, int C) {
  __shared__ float tile[32][33];
  const int tid = threadIdx.x;
  const size_t zoff = (size_t)blockIdx.z * R * C;
  const int r0 = blockIdx.y * 32, c0 = blockIdx.x * 32;
  const int tx = tid & 31, ty = tid >> 5;
  #pragma unroll
  for (int i = 0; i < 4; ++i)
    tile[ty + i * 8][tx] = src[zoff + (size_t)(r0 + ty + i * 8) * C + c0 + tx];
  __syncthreads();
  #pragma unroll
  for (int i = 0; i < 4; ++i)
    dst[zoff + (size_t)(c0 + ty + i * 8) * R + r0 + tx] = f2bf(tile[tx][ty + i * 8]);
}

// --------------------------- final combine ---------------------------------
__global__ __launch_bounds__(256) void combine_k(const float* __restrict__ x2,
                                                 const float* __restrict__ ye,
                                                 const int*   __restrict__ tok_e,
                                                 const float* __restrict__ tok_g,
                                                 const int*   __restrict__ tok_p,
                                                 float* __restrict__ out) {
  const int t = blockIdx.x, tid = threadIdx.x;
  float4 v = ((const float4*)(x2 + (size_t)t * D_))[tid];
  #pragma unroll
  for (int r = 0; r < 2; ++r) {
    const int p = tok_p[2 * t + r];
    if (p >= 0) {
      const int e = tok_e[2 * t + r];
      const float g = tok_g[2 * t + r];
      const float4 y = ((const float4*)(ye + (size_t)(e * CAP_ + p) * D_))[tid];
      v.x = fmaf(g, y.x, v.x);
      v.y = fmaf(g, y.y, v.y);
      v.z = fmaf(g, y.z, v.z);
      v.w = fmaf(g, y.w, v.w);
    }
  }
  ((float4*)(out + (size_t)t * D_))[tid] = v;
}

// ---------------------------------------------------------------------------
extern "C" void kernel_launch(void* const* d_in, const int* in_sizes, int n_in,
                              void* d_out, int out_size, void* d_ws, size_t ws_size,
                              hipStream_t stream) {
  const float* x    = (const float*)d_in[0];
  const float* g1   = (const float*)d_in[1];
  const float* wqkv = (const float*)d_in[2];
  const float* wo   = (const float*)d_in[3];
  const float* g2   = (const float*)d_in[4];
  const float* wr   = (const float*)d_in[5];
  const float* w1   = (const float*)d_in[6];
  const float* w2   = (const float*)d_in[7];
  float* out = (float*)d_out;
  char* ws = (char*)d_ws;
  const size_t MB = 1ull << 20;

  // Phase-aliased workspace layout (~233 MB):
  u16*   y1hh  = (u16*)  (ws + 0);          // 8MB  fp16-hi of rmsnorm1 out; reused as qhi
  u16*   y1hl  = (u16*)  (ws + 8 * MB);     // 8MB  fp16-lo; reused as qlo
  u16*   ahh   = (u16*)  (ws + 16 * MB);    // 8MB  attn out fp16-hi
  u16*   ahl   = (u16*)  (ws + 24 * MB);    // 8MB  attn out fp16-lo
  u16*   hbf   = (u16*)  (ws + 0);          // 40MB MoE hidden (aliases the above)
  float* qkv   = (float*)(ws + 40 * MB);    // 48MB, dead after rope/v split
  float* PO    = (float*)(ws + 40 * MB);    // 16.8MB attn split-K partials (after vsplit)
  float* Pm    = (float*)(ws + 58 * MB);    // 0.26MB
  float* Pl2   = (float*)(ws + 59 * MB);    // 0.26MB
  u16*   xe    = (u16*)  (ws + 40 * MB);    // 20MB, aliases qkv/PO (MoE time)
  float* x2    = (float*)(ws + 88 * MB);    // 16MB
  float* y2    = (float*)(ws + 104 * MB);   // 16MB (fp32 for router!)
  u16*   y2b   = (u16*)  (ws + 120 * MB);   // 8MB
  u16*   w1t   = (u16*)  (ws + 128 * MB);   // 32MB  [E][FFN][D] bf16
  u16*   w2t   = (u16*)  (ws + 160 * MB);   // 32MB  [E][D][FFN] bf16
  float* ye    = (float*)(ws + 192 * MB);   // 40MB (MoE time)
  u16*   wqh   = (u16*)  (ws + 192 * MB);   // 6MB  w_qkv^T fp16-hi (dead before rope)
  u16*   wql   = (u16*)  (ws + 198 * MB);   // 6MB  fp16-lo
  u16*   khi   = (u16*)  (ws + 192 * MB);   // 8MB  (after QKV gemm)
  u16*   klo   = (u16*)  (ws + 200 * MB);   // 8MB
  u16*   vthi  = (u16*)  (ws + 208 * MB);   // 8MB
  u16*   vtlo  = (u16*)  (ws + 216 * MB);   // 8MB
  u16*   woh   = (u16*)  (ws + 224 * MB);   // 2MB  w_o^T fp16-hi (dead before MoE ye)
  u16*   wol   = (u16*)  (ws + 226 * MB);   // 2MB
  int*   cnt   = (int*)  (ws + 232 * MB);
  int*   tok_e = cnt + 16;                  // 2*T
  float* tok_g = (float*)(tok_e + 2 * T_);  // 2*T
  int*   tok_p = (int*)  (tok_g + 2 * T_);  // 2*T
  int*   etok  = tok_p + 2 * T_;            // E*CAP

  init_k<<<1, 64, 0, stream>>>(cnt);
  transpose_bf_k<<<dim3(FFN_/32, D_/32, E_), 256, 0, stream>>>(w1, w1t, D_, FFN_);
  transpose_bf_k<<<dim3(D_/32, FFN_/32, E_), 256, 0, stream>>>(w2, w2t, FFN_, D_);
  // w_qkv (Dx3D) -> [3D][D] fp16 hi/lo; w_o (DxD) -> [D][D] fp16 hi/lo
  wsplit_t_k<<<dim3(3*D_/32, D_/32), 256, 0, stream>>>(wqkv, wqh, wql, D_, 3*D_);
  wsplit_t_k<<<dim3(D_/32, D_/32), 256, 0, stream>>>(wo, woh, wol, D_, D_);

  // x -> rmsnorm -> y1 (fp16 hi/lo only)
  rmsnorm_k<<<T_, 256, 0, stream>>>(x, g1, (float*)nullptr, (u16*)nullptr, y1hh, y1hl);
  // qkv = y1 @ w_qkv via split-fp16 MFMA (fp32 out)
  gemm_split<false><<<dim3(3 * D_ / 128, T_ / 128), 256, 0, stream>>>(
      y1hh, y1hl, wqh, wql, nullptr, qkv, D_, D_, D_, 3 * D_);
  // RoPE + split q,k (q pre-scaled by 1/8); y1hh/y1hl are dead -> reuse as qhi/qlo
  ropesplit_k<<<T_ * H_ * 32 / 256, 256, 0, stream>>>(qkv, y1hh, y1hl, khi, klo);
  vsplit_k<<<dim3(S_ / 64, B_ * H_), 256, 0, stream>>>(qkv, vthi, vtlo);
  // split-bf16 MFMA flash attention (split-K) -> fp16 hi/lo + partials
  attn_mfma_k<<<dim3(48, B_ * H_), 256, 0, stream>>>(
      y1hh, y1hl, khi, klo, vthi, vtlo, ahh, ahl, PO, Pm, Pl2);
  attn_combine_k<<<dim3(16, B_ * H_), 256, 0, stream>>>(PO, Pm, Pl2, ahh, ahl);
  // x2 = attn @ w_o + x via split-fp16 MFMA
  gemm_split<true><<<dim3(D_ / 128, T_ / 128), 256, 0, stream>>>(
      ahh, ahl, woh, wol, x, x2, D_, D_, D_, D_);
  // x2 -> rmsnorm -> y2 (fp32) + y2b (bf16)
  rmsnorm_k<<<T_, 256, 0, stream>>>(x2, g2, y2, y2b, (u16*)nullptr, (u16*)nullptr);
  // router (fp32 logits, top-2, capacity assignment)
  router_k<<<T_ / 4, 256, 0, stream>>>(y2, wr, cnt, tok_e, tok_g, tok_p, etok);
  // gather per-expert token rows (bf16)
  gather_k<<<dim3(CAP_, E_), 256, 0, stream>>>(y2b, etok, cnt, xe);
  // h = relu(xe @ w1) (bf16 out), batched over experts
  gemm_bt<u16, true><<<dim3(FFN_/128, CAP_/128, E_), 256, 0, stream>>>(
      xe, w1t, hbf, CAP_, FFN_, D_, D_, D_, FFN_,
      (long)CAP_ * D_, (long)FFN_ * D_, (long)CAP_ * FFN_);
  // ye = h @ w2 (fp32 out)
  gemm_bt<float, false><<<dim3(D_/128, CAP_/128, E_), 256, 0, stream>>>(
      hbf, w2t, ye, CAP_, D_, FFN_, FFN_, FFN_, D_,
      (long)CAP_ * FFN_, (long)D_ * FFN_, (long)CAP_ * D_);
  // out = x2 + sum_r gate_r * ye[...]
  combine_k<<<T_, 256, 0, stream>>>(x2, ye, tok_e, tok_g, tok_p, out);
}

// Round 5
// 747.102 us; speedup vs baseline: 3.2586x; 1.0625x over previous
//
#include <hip/hip_runtime.h>
#include <math.h>

// ---------------------------------------------------------------------------
// Fused transformer block on MI355X.
// Precision: all pre-router math is fp32-equivalent (split-fp16/bf16 MFMA),
// post-routing MoE GEMMs plain bf16 MFMA.
// R5: attention restructured — S computed transposed so P exits QK^T already
// in the K=16 MFMA A-operand layout; PV chains mfma_f32_16x16x16f16 directly
// from registers (no P LDS round-trip). V pre-packed in B-operand layout
// (fp16 hi/lo interleaved) and staged via global_load_lds. LDS 52->34KB.
// ---------------------------------------------------------------------------

#define B_   2
#define S_   2048
#define D_   1024
#define H_   16
#define HD_  64
#define FFN_ 2048
#define E_   8
#define CAP_ 1280
#define T_   (B_*S_)

typedef unsigned short u16;
typedef __attribute__((ext_vector_type(8))) short     short8;    // MFMA bf16x8 operand
typedef __attribute__((ext_vector_type(8))) _Float16  half8;     // MFMA f16x8 operand
typedef __attribute__((ext_vector_type(4))) _Float16  half4;     // K=16 MFMA f16x4 operand
typedef __attribute__((ext_vector_type(8))) unsigned short ushort8v;
typedef __attribute__((ext_vector_type(4))) float     f32x4;

__device__ __forceinline__ u16 f2bf(float f) {
  unsigned u = __float_as_uint(f);
  return (u16)((u + 0x7fffu + ((u >> 16) & 1u)) >> 16);   // RNE
}
__device__ __forceinline__ float bf2f(u16 h) {
  return __uint_as_float(((unsigned)h) << 16);
}
__device__ __forceinline__ u16 f2h(float f) {
  _Float16 h = (_Float16)f;
  return __builtin_bit_cast(u16, h);
}
__device__ __forceinline__ float h2f(u16 b) {
  return (float)__builtin_bit_cast(_Float16, b);
}

__device__ __forceinline__ void cstore(float* p, float v) { *p = v; }
__device__ __forceinline__ void cstore(u16* p, float v)   { *p = f2bf(v); }

// global -> LDS direct DMA, 16B per lane (lane-linear dest).
__device__ __forceinline__ void glds16(const u16* g, u16* l) {
  __builtin_amdgcn_global_load_lds(
      (const __attribute__((address_space(1))) unsigned int*)g,
      (__attribute__((address_space(3))) unsigned int*)l, 16, 0, 0);
}

// --------------------------- init: zero expert counters --------------------
__global__ void init_k(int* cnt) {
  if (threadIdx.x < 16) cnt[threadIdx.x] = 0;
}

// --------------------------- RMSNorm (fp32 in; fp32/bf16/fp16-split out) ---
__global__ __launch_bounds__(256) void rmsnorm_k(const float* __restrict__ x,
                                                 const float* __restrict__ g,
                                                 float* __restrict__ of,
                                                 u16*   __restrict__ ob,
                                                 u16*   __restrict__ ohh,
                                                 u16*   __restrict__ ohl) {
  const int t = blockIdx.x, tid = threadIdx.x;
  const float4 xv = ((const float4*)(x + (size_t)t * D_))[tid];
  float ss = xv.x*xv.x + xv.y*xv.y + xv.z*xv.z + xv.w*xv.w;
  #pragma unroll
  for (int off = 32; off; off >>= 1) ss += __shfl_down(ss, off);
  __shared__ float wsum[4];
  if ((tid & 63) == 0) wsum[tid >> 6] = ss;
  __syncthreads();
  const float tot = wsum[0] + wsum[1] + wsum[2] + wsum[3];
  const float rms = 1.0f / sqrtf(tot * (1.0f / D_) + 1e-6f);
  const float4 gv = ((const float4*)g)[tid];
  float4 o;
  o.x = gv.x * xv.x * rms;
  o.y = gv.y * xv.y * rms;
  o.z = gv.z * xv.z * rms;
  o.w = gv.w * xv.w * rms;
  if (of) ((float4*)(of + (size_t)t * D_))[tid] = o;
  if (ob) {
    ushort4 h;
    h.x = f2bf(o.x); h.y = f2bf(o.y); h.z = f2bf(o.z); h.w = f2bf(o.w);
    ((ushort4*)(ob + (size_t)t * D_))[tid] = h;
  }
  if (ohh) {
    ushort4 hh, hl;
    hh.x = f2h(o.x); hl.x = f2h(o.x - h2f(hh.x));
    hh.y = f2h(o.y); hl.y = f2h(o.y - h2f(hh.y));
    hh.z = f2h(o.z); hl.z = f2h(o.z - h2f(hh.z));
    hh.w = f2h(o.w); hl.w = f2h(o.w - h2f(hh.w));
    ((ushort4*)(ohh + (size_t)t * D_))[tid] = hh;
    ((ushort4*)(ohl + (size_t)t * D_))[tid] = hl;
  }
}

// --------------------------- split-fp16 MFMA GEMM: C = (A)(Bt)^T (+resid) --
template<bool RESID>
__global__ __launch_bounds__(256) void gemm_split(const u16* __restrict__ Ah,
                                                  const u16* __restrict__ Al,
                                                  const u16* __restrict__ Bh,
                                                  const u16* __restrict__ Bl,
                                                  const float* __restrict__ resid,
                                                  float* __restrict__ C,
                                                  int K, int lda, int ldb, int ldc) {
  __shared__ u16 AsH[128 * 32], AsL[128 * 32];
  __shared__ u16 BsH[128 * 32], BsL[128 * 32];
  const int tid = threadIdx.x;
  const int bm = blockIdx.y, bn = blockIdx.x;
  const int lane = tid & 63, wave = tid >> 6;
  const int wy = wave >> 1, wx = wave & 1;
  const int l15 = lane & 15, lq = lane >> 4;
  f32x4 acc[4][4];
  #pragma unroll
  for (int i = 0; i < 4; ++i)
    #pragma unroll
    for (int j = 0; j < 4; ++j)
      #pragma unroll
      for (int r = 0; r < 4; ++r) acc[i][j][r] = 0.0f;
  const int srow = lane >> 2, skc = (lane & 3) * 8;
  size_t ga[2], gb[2];
  int ldsoff[2];
  #pragma unroll
  for (int c = 0; c < 2; ++c) {
    const int q = wave * 2 + c;
    ga[c] = (size_t)(bm * 128 + q * 16 + srow) * lda + skc;
    gb[c] = (size_t)(bn * 128 + q * 16 + srow) * ldb + skc;
    ldsoff[c] = q * 512 + lane * 8;
  }

  for (int kt = 0; kt < K; kt += 32) {
    __syncthreads();
    #pragma unroll
    for (int c = 0; c < 2; ++c) {
      glds16(Ah + ga[c] + kt, &AsH[ldsoff[c]]);
      glds16(Al + ga[c] + kt, &AsL[ldsoff[c]]);
      glds16(Bh + gb[c] + kt, &BsH[ldsoff[c]]);
      glds16(Bl + gb[c] + kt, &BsL[ldsoff[c]]);
    }
    __syncthreads();
    half8 ah[4], al[4], bh[4], bl[4];
    #pragma unroll
    for (int i = 0; i < 4; ++i) {
      const int row = (wy * 64 + i * 16 + l15) * 32 + lq * 8;
      ah[i] = *(const half8*)&AsH[row];
      al[i] = *(const half8*)&AsL[row];
    }
    #pragma unroll
    for (int j = 0; j < 4; ++j) {
      const int row = (wx * 64 + j * 16 + l15) * 32 + lq * 8;
      bh[j] = *(const half8*)&BsH[row];
      bl[j] = *(const half8*)&BsL[row];
    }
    #pragma unroll
    for (int i = 0; i < 4; ++i)
      #pragma unroll
      for (int j = 0; j < 4; ++j) {
        acc[i][j] = __builtin_amdgcn_mfma_f32_16x16x32_f16(ah[i], bh[j], acc[i][j], 0, 0, 0);
        acc[i][j] = __builtin_amdgcn_mfma_f32_16x16x32_f16(ah[i], bl[j], acc[i][j], 0, 0, 0);
        acc[i][j] = __builtin_amdgcn_mfma_f32_16x16x32_f16(al[i], bh[j], acc[i][j], 0, 0, 0);
      }
  }
  #pragma unroll
  for (int i = 0; i < 4; ++i)
    #pragma unroll
    for (int j = 0; j < 4; ++j)
      #pragma unroll
      for (int r = 0; r < 4; ++r) {
        const int row = bm * 128 + wy * 64 + i * 16 + lq * 4 + r;
        const int col = bn * 128 + wx * 64 + j * 16 + l15;
        float v = acc[i][j][r];
        if (RESID) v += resid[(size_t)row * ldc + col];
        C[(size_t)row * ldc + col] = v;
      }
}

// --------------------------- weight transpose + fp16 split -----------------
__global__ __launch_bounds__(256) void wsplit_t_k(const float* __restrict__ src,
                                                  u16* __restrict__ dh,
                                                  u16* __restrict__ dl,
                                                  int R, int C) {
  __shared__ float tile[32][33];
  const int tid = threadIdx.x;
  const int r0 = blockIdx.y * 32, c0 = blockIdx.x * 32;
  const int tx = tid & 31, ty = tid >> 5;
  #pragma unroll
  for (int i = 0; i < 4; ++i)
    tile[ty + i * 8][tx] = src[(size_t)(r0 + ty + i * 8) * C + c0 + tx];
  __syncthreads();
  #pragma unroll
  for (int i = 0; i < 4; ++i) {
    const float v = tile[tx][ty + i * 8];
    const u16 hh = f2h(v);
    const size_t o = (size_t)(c0 + ty + i * 8) * R + r0 + tx;
    dh[o] = hh;
    dl[o] = f2h(v - h2f(hh));
  }
}

// --------------------------- RoPE + split q,k -> bf16 hi/lo ----------------
__global__ __launch_bounds__(256) void ropesplit_k(const float* __restrict__ qkv,
                                                   u16* __restrict__ qhi, u16* __restrict__ qlo,
                                                   u16* __restrict__ khi, u16* __restrict__ klo) {
  const int i = blockIdx.x * 256 + threadIdx.x;   // over T_*H_*32
  const int j = i & 31;
  const int h = (i >> 5) & 15;
  const int t = i >> 9;
  const int s = t & (S_ - 1);
  const int b = t >> 11;
  const int bh = b * 16 + h;
  const float theta = (float)pow(10000.0, -(double)j / 32.0);
  const float fr = (float)s * theta;
  const float c = cosf(fr), sn = sinf(fr);
  const float2 q = *(const float2*)(qkv + (size_t)t * 3072 + h * 64 + 2 * j);
  const float2 k = *(const float2*)(qkv + (size_t)t * 3072 + 1024 + h * 64 + 2 * j);
  const float q0 = (q.x * c - q.y * sn) * 0.125f;
  const float q1 = (q.x * sn + q.y * c) * 0.125f;
  const float k0 = k.x * c - k.y * sn;
  const float k1 = k.x * sn + k.y * c;
  const size_t o = ((size_t)bh * S_ + s) * 32 + j;   // uint (2xu16) index
  const u16 qh0 = f2bf(q0), qh1 = f2bf(q1);
  const u16 kh0 = f2bf(k0), kh1 = f2bf(k1);
  ((unsigned*)qhi)[o] = (unsigned)qh0 | ((unsigned)qh1 << 16);
  ((unsigned*)khi)[o] = (unsigned)kh0 | ((unsigned)kh1 << 16);
  const u16 ql0 = f2bf(q0 - bf2f(qh0)), ql1 = f2bf(q1 - bf2f(qh1));
  const u16 kl0 = f2bf(k0 - bf2f(kh0)), kl1 = f2bf(k1 - bf2f(kh1));
  ((unsigned*)qlo)[o] = (unsigned)ql0 | ((unsigned)ql1 << 16);
  ((unsigned*)klo)[o] = (unsigned)kl0 | ((unsigned)kl1 << 16);
}

// --------------------------- V pack: fp16 hi/lo in K=16 B-operand layout ---
// Per (bh, key-tile kt): group g=(kc*4+n)*64+lane holds 8 u16:
// [ V[kt*64+kc*16+(lane>>4)*4+j][n*16+(lane&15)] hi j=0..3 | lo j=0..3 ]
__global__ __launch_bounds__(256) void vpack_k(const float* __restrict__ qkv,
                                               u16* __restrict__ vpk) {
  const int kt = blockIdx.x, bh = blockIdx.y;
  const int b = bh >> 4, h = bh & 15;
  const int tid = threadIdx.x;
  u16* dst = vpk + (size_t)(bh * 32 + kt) * 8192;
  #pragma unroll
  for (int i = 0; i < 4; ++i) {
    const int g = i * 256 + tid;               // 0..1023
    const int lane = g & 63, n = (g >> 6) & 3, kc = g >> 8;
    const int lq = lane >> 4, l15 = lane & 15;
    const int key = kt * 64 + kc * 16 + lq * 4;
    const int d = n * 16 + l15;
    u16 out[8];
    #pragma unroll
    for (int j = 0; j < 4; ++j) {
      const float v = qkv[(size_t)(b * S_ + key + j) * 3072 + 2048 + h * 64 + d];
      const u16 hh = f2h(v);
      out[j] = hh;
      out[4 + j] = f2h(v - h2f(hh));
    }
    *(ushort8v*)(dst + g * 8) = *(ushort8v*)out;
  }
}

// --------------------------- MFMA flash attention (split-K, chained PV) ----
// S computed transposed: mfma(A=K, B=Q) -> C-layout query=l15, key=lq*4+r,
// which IS the K=16 A-operand layout. PV chains mfma_f32_16x16x16f16 from
// registers (split-fp16 P and V). No P LDS round-trip.
__global__ __launch_bounds__(256) void attn_mfma_k(const u16* __restrict__ qhi,
                                                   const u16* __restrict__ qlo,
                                                   const u16* __restrict__ khi,
                                                   const u16* __restrict__ klo,
                                                   const u16* __restrict__ vpk,
                                                   u16* __restrict__ ahh,
                                                   u16* __restrict__ ahl,
                                                   float* __restrict__ PO,
                                                   float* __restrict__ Pm,
                                                   float* __restrict__ Pl2) {
  __shared__ u16 Kh[64 * 68], Kl[64 * 68];   // [key][dim], padded
  __shared__ u16 Vp[8192];                   // packed fp16 hi/lo B-operand
  const int tid = threadIdx.x, lane = tid & 63, wave = tid >> 6;
  const int bi = blockIdx.x;
  int qt, k0, k1, chunk;
  bool partial;
  if (bi < 32) {
    qt = 31 - (bi >> 1); chunk = bi & 1;
    const int nk = qt + 1, cut = nk >> 1;
    k0 = chunk ? cut : 0;
    k1 = chunk ? nk : cut;
    partial = true;
  } else {
    qt = 47 - bi; chunk = 0; k0 = 0; k1 = qt + 1; partial = false;
  }
  const int bh = blockIdx.y;
  const int l15 = lane & 15, lq = lane >> 4;
  const size_t hb = (size_t)bh * S_ * 64;
  // Q as B-operand: lane n=l15 -> query, k=lq*8+j (same per-lane data as A).
  const int qrow = qt * 64 + wave * 16 + l15;
  short8 qh[2], ql[2];
  qh[0] = *(const short8*)(qhi + hb + (size_t)qrow * 64 + lq * 8);
  qh[1] = *(const short8*)(qhi + hb + (size_t)qrow * 64 + 32 + lq * 8);
  ql[0] = *(const short8*)(qlo + hb + (size_t)qrow * 64 + lq * 8);
  ql[1] = *(const short8*)(qlo + hb + (size_t)qrow * 64 + 32 + lq * 8);
  f32x4 O[4];
  #pragma unroll
  for (int n = 0; n < 4; ++n)
    #pragma unroll
    for (int r = 0; r < 4; ++r) O[n][r] = 0.0f;
  float m_i = -__builtin_inff(), l_i = 0.0f;  // for query = wave*16 + l15

  for (int kt = k0; kt < k1; ++kt) {
    __syncthreads();
    // stage V packed tile via DMA (lane-linear)
    {
      const u16* vg = vpk + (size_t)(bh * 32 + kt) * 8192 + wave * 2048;
      #pragma unroll
      for (int c = 0; c < 4; ++c)
        glds16(vg + c * 512 + lane * 8, &Vp[wave * 2048 + c * 512 + lane * 8]);
    }
    // stage K hi/lo (padded rows for conflict-free b128 reads)
    #pragma unroll
    for (int it = 0; it < 2; ++it) {
      const int idx = it * 256 + tid;
      const int row = idx >> 3, c8 = (idx & 7) * 8;
      const size_t koff = hb + (size_t)(kt * 64 + row) * 64 + c8;
      *(ushort8v*)&Kh[row * 68 + c8] = *(const ushort8v*)(khi + koff);
      *(ushort8v*)&Kl[row * 68 + c8] = *(const ushort8v*)(klo + koff);
    }
    __syncthreads();
    // ---- S^T = K Q^T (3-product split): sc[kc][r]: key=kc*16+lq*4+r,
    //      query=wave*16+l15 ----
    f32x4 sc[4];
    #pragma unroll
    for (int kc = 0; kc < 4; ++kc)
      #pragma unroll
      for (int r = 0; r < 4; ++r) sc[kc][r] = 0.0f;
    #pragma unroll
    for (int kc = 0; kc < 4; ++kc) {
      const int krow = (kc * 16 + l15) * 68 + lq * 8;
      const short8 kb0 = *(const short8*)&Kh[krow];
      const short8 kb1 = *(const short8*)&Kh[krow + 32];
      const short8 kl0 = *(const short8*)&Kl[krow];
      const short8 kl1 = *(const short8*)&Kl[krow + 32];
      sc[kc] = __builtin_amdgcn_mfma_f32_16x16x32_bf16(kb0, qh[0], sc[kc], 0, 0, 0);
      sc[kc] = __builtin_amdgcn_mfma_f32_16x16x32_bf16(kb1, qh[1], sc[kc], 0, 0, 0);
      sc[kc] = __builtin_amdgcn_mfma_f32_16x16x32_bf16(kb0, ql[0], sc[kc], 0, 0, 0);
      sc[kc] = __builtin_amdgcn_mfma_f32_16x16x32_bf16(kb1, ql[1], sc[kc], 0, 0, 0);
      sc[kc] = __builtin_amdgcn_mfma_f32_16x16x32_bf16(kl0, qh[0], sc[kc], 0, 0, 0);
      sc[kc] = __builtin_amdgcn_mfma_f32_16x16x32_bf16(kl1, qh[1], sc[kc], 0, 0, 0);
    }
    // ---- causal mask on the diagonal tile ----
    if (kt == qt) {
      #pragma unroll
      for (int kc = 0; kc < 4; ++kc)
        #pragma unroll
        for (int r = 0; r < 4; ++r)
          if (kc * 16 + lq * 4 + r > wave * 16 + l15) sc[kc][r] = -__builtin_inff();
    }
    // ---- online softmax: row (query) state is per-lane scalar ----
    float mx = -__builtin_inff();
    #pragma unroll
    for (int kc = 0; kc < 4; ++kc)
      #pragma unroll
      for (int r = 0; r < 4; ++r) mx = fmaxf(mx, sc[kc][r]);
    mx = fmaxf(mx, __shfl_xor(mx, 16));
    mx = fmaxf(mx, __shfl_xor(mx, 32));
    const float mn = fmaxf(m_i, mx);
    const float alpha = __expf(m_i - mn);
    m_i = mn;
    f32x4 p[4];
    float rs = 0.0f;
    #pragma unroll
    for (int kc = 0; kc < 4; ++kc)
      #pragma unroll
      for (int r = 0; r < 4; ++r) { p[kc][r] = __expf(sc[kc][r] - m_i); rs += p[kc][r]; }
    rs += __shfl_xor(rs, 16);
    rs += __shfl_xor(rs, 32);
    l_i = l_i * alpha + rs;
    // rescale O: O[n][r] belongs to query lq*4+r -> fetch that query's alpha
    #pragma unroll
    for (int r = 0; r < 4; ++r) {
      const float alr = __shfl(alpha, lq * 4 + r);
      #pragma unroll
      for (int n = 0; n < 4; ++n) O[n][r] *= alr;
    }
    // ---- P -> split-fp16 in registers (K=16 A-operand layout) ----
    half4 ph[4], pl[4];
    #pragma unroll
    for (int kc = 0; kc < 4; ++kc)
      #pragma unroll
      for (int r = 0; r < 4; ++r) {
        const _Float16 hi = (_Float16)p[kc][r];
        ph[kc][r] = hi;
        pl[kc][r] = (_Float16)(p[kc][r] - (float)hi);
      }
    // ---- O += P V, chained K=16 MFMAs (hh, hl, lh) ----
    #pragma unroll
    for (int n = 0; n < 4; ++n)
      #pragma unroll
      for (int kc = 0; kc < 4; ++kc) {
        const int g = ((kc * 4 + n) * 64 + lane) * 8;
        const half4 vh = *(const half4*)&Vp[g];
        const half4 vl = *(const half4*)&Vp[g + 4];
        O[n] = __builtin_amdgcn_mfma_f32_16x16x16f16(ph[kc], vh, O[n], 0, 0, 0);
        O[n] = __builtin_amdgcn_mfma_f32_16x16x16f16(ph[kc], vl, O[n], 0, 0, 0);
        O[n] = __builtin_amdgcn_mfma_f32_16x16x16f16(pl[kc], vh, O[n], 0, 0, 0);
      }
  }
  const int b = bh >> 4, h = bh & 15;
  if (!partial) {
    #pragma unroll
    for (int r = 0; r < 4; ++r) {
      const float lr = __shfl(l_i, lq * 4 + r);
      const float inv = 1.0f / lr;
      const int row = qt * 64 + wave * 16 + lq * 4 + r;
      const size_t base = (size_t)(b * S_ + row) * D_ + h * 64 + l15;
      #pragma unroll
      for (int n = 0; n < 4; ++n) {
        const float o = O[n][r] * inv;
        const u16 hh = f2h(o);
        ahh[base + n * 16] = hh;
        ahl[base + n * 16] = f2h(o - h2f(hh));
      }
    }
  } else {
    // unnormalized partials; rows are >= 1024 since qt >= 16
    #pragma unroll
    for (int r = 0; r < 4; ++r) {
      const int prow = qt * 64 + wave * 16 + lq * 4 + r - 1024;
      const size_t idx = (size_t)(chunk * 32 + bh) * 1024 + prow;
      float* po = PO + idx * 64;
      #pragma unroll
      for (int n = 0; n < 4; ++n) po[n * 16 + l15] = O[n][r];
    }
    if (lq == 0) {   // lane holds m/l for query wave*16 + l15
      const int prow = qt * 64 + wave * 16 + l15 - 1024;
      const size_t idx = (size_t)(chunk * 32 + bh) * 1024 + prow;
      Pm[idx] = m_i; Pl2[idx] = l_i;
    }
  }
}

// --------------------------- combine split-K attention partials ------------
__global__ __launch_bounds__(256) void attn_combine_k(const float* __restrict__ PO,
                                                      const float* __restrict__ Pm,
                                                      const float* __restrict__ Pl2,
                                                      u16* __restrict__ ahh,
                                                      u16* __restrict__ ahl) {
  const int tid = threadIdx.x;
  const int bh = blockIdx.y, b = bh >> 4, h = bh & 15;
  const int prow = blockIdx.x * 64 + (tid >> 2);
  const int d0 = (tid & 3) * 16;
  const size_t i0 = (size_t)bh * 1024 + prow;
  const size_t i1 = (size_t)(32 + bh) * 1024 + prow;
  const float m0 = Pm[i0], m1 = Pm[i1];
  const float M = fmaxf(m0, m1);
  const float w0 = __expf(m0 - M), w1 = __expf(m1 - M);
  const float inv = 1.0f / (w0 * Pl2[i0] + w1 * Pl2[i1]);
  const int row = 1024 + prow;
  const size_t ob = (size_t)(b * S_ + row) * D_ + h * 64 + d0;
  #pragma unroll
  for (int q4 = 0; q4 < 4; ++q4) {
    const float4 o0 = *(const float4*)(PO + i0 * 64 + d0 + q4 * 4);
    const float4 o1 = *(const float4*)(PO + i1 * 64 + d0 + q4 * 4);
    float v[4];
    v[0] = (w0 * o0.x + w1 * o1.x) * inv;
    v[1] = (w0 * o0.y + w1 * o1.y) * inv;
    v[2] = (w0 * o0.z + w1 * o1.z) * inv;
    v[3] = (w0 * o0.w + w1 * o1.w) * inv;
    ushort4 hh, hl;
    u16* ph = (u16*)&hh;
    u16* pl = (u16*)&hl;
    #pragma unroll
    for (int z = 0; z < 4; ++z) {
      ph[z] = f2h(v[z]);
      pl[z] = f2h(v[z] - h2f(ph[z]));
    }
    *(ushort4*)(ahh + ob + q4 * 4) = hh;
    *(ushort4*)(ahl + ob + q4 * 4) = hl;
  }
}

// --------------------------- router: logits + top2 + capacity assign -------
__global__ __launch_bounds__(256) void router_k(const float* __restrict__ y2,
                                                const float* __restrict__ wr,
                                                int*   __restrict__ cnt,
                                                int*   __restrict__ tok_e,
                                                float* __restrict__ tok_g,
                                                int*   __restrict__ tok_p,
                                                int*   __restrict__ etok) {
  const int wave = threadIdx.x >> 6, lane = threadIdx.x & 63;
  const int t = blockIdx.x * 4 + wave;
  const float* xr = y2 + (size_t)t * D_;
  float acc[8];
  #pragma unroll
  for (int e = 0; e < 8; ++e) acc[e] = 0.0f;
  for (int c = 0; c < 16; ++c) {
    const float xv = xr[c * 64 + lane];
    const float* w = wr + (size_t)(c * 64 + lane) * 8;
    #pragma unroll
    for (int e = 0; e < 8; ++e) acc[e] = fmaf(xv, w[e], acc[e]);
  }
  #pragma unroll
  for (int off = 32; off; off >>= 1)
    #pragma unroll
    for (int e = 0; e < 8; ++e) acc[e] += __shfl_down(acc[e], off);
  if (lane == 0) {
    float mx = acc[0];
    #pragma unroll
    for (int e = 1; e < 8; ++e) mx = fmaxf(mx, acc[e]);
    float ex[8], sum = 0.0f;
    #pragma unroll
    for (int e = 0; e < 8; ++e) { ex[e] = expf(acc[e] - mx); sum += ex[e]; }
    int e1 = 0;
    #pragma unroll
    for (int e = 1; e < 8; ++e) if (acc[e] > acc[e1]) e1 = e;
    int e2 = (e1 == 0) ? 1 : 0;
    #pragma unroll
    for (int e = 0; e < 8; ++e) if (e != e1 && acc[e] > acc[e2]) e2 = e;
    const float g1v = ex[e1] / sum, g2v = ex[e2] / sum;
    int p1 = atomicAdd(&cnt[e1], 1);
    int p2 = atomicAdd(&cnt[e2], 1);
    if (p1 < CAP_) etok[e1 * CAP_ + p1] = t; else p1 = -1;
    if (p2 < CAP_) etok[e2 * CAP_ + p2] = t; else p2 = -1;
    tok_e[2*t] = e1;   tok_e[2*t+1] = e2;
    tok_g[2*t] = g1v;  tok_g[2*t+1] = g2v;
    tok_p[2*t] = p1;   tok_p[2*t+1] = p2;
  }
}

// --------------------------- gather tokens per expert (bf16) ---------------
__global__ __launch_bounds__(256) void gather_k(const u16* __restrict__ y2b,
                                                const int* __restrict__ etok,
                                                const int* __restrict__ cnt,
                                                u16* __restrict__ xe) {
  const int e = blockIdx.y, pos = blockIdx.x, tid = threadIdx.x;
  const int n = min(cnt[e], CAP_);
  ushort4* dst = (ushort4*)(xe + (size_t)(e * CAP_ + pos) * D_) + tid;
  if (pos < n) {
    const int t = etok[e * CAP_ + pos];
    *dst = ((const ushort4*)(y2b + (size_t)t * D_))[tid];
  } else {
    *dst = make_ushort4(0, 0, 0, 0);
  }
}

// --------------------------- bf16 MFMA GEMM: C = A * Bt^T ------------------
template<typename OT, bool RELU>
__global__ __launch_bounds__(256) void gemm_bt(const u16* __restrict__ A,
                                               const u16* __restrict__ Bt,
                                               OT* __restrict__ C,
                                               int M, int N, int K,
                                               int lda, int ldb, int ldc,
                                               long sAz, long sBz, long sCz) {
  __shared__ u16 As[128 * 32];
  __shared__ u16 Bs[128 * 32];
  const int tid = threadIdx.x;
  A  += (size_t)blockIdx.z * sAz;
  Bt += (size_t)blockIdx.z * sBz;
  C  += (size_t)blockIdx.z * sCz;
  const int bm = blockIdx.y, bn = blockIdx.x;
  const int lane = tid & 63, wave = tid >> 6;
  const int wy = wave >> 1, wx = wave & 1;
  const int l15 = lane & 15, lq = lane >> 4;
  f32x4 acc[4][4];
  #pragma unroll
  for (int i = 0; i < 4; ++i)
    #pragma unroll
    for (int j = 0; j < 4; ++j)
      #pragma unroll
      for (int r = 0; r < 4; ++r) acc[i][j][r] = 0.0f;
  const int srow = lane >> 2, skc = (lane & 3) * 8;
  size_t ga[2], gb[2];
  int ldsoff[2];
  #pragma unroll
  for (int c = 0; c < 2; ++c) {
    const int q = wave * 2 + c;
    ga[c] = (size_t)(bm * 128 + q * 16 + srow) * lda + skc;
    gb[c] = (size_t)(bn * 128 + q * 16 + srow) * ldb + skc;
    ldsoff[c] = q * 512 + lane * 8;
  }

  for (int kt = 0; kt < K; kt += 32) {
    __syncthreads();
    #pragma unroll
    for (int c = 0; c < 2; ++c) {
      glds16(A  + ga[c] + kt, &As[ldsoff[c]]);
      glds16(Bt + gb[c] + kt, &Bs[ldsoff[c]]);
    }
    __syncthreads();
    short8 a[4], b[4];
    #pragma unroll
    for (int i = 0; i < 4; ++i)
      a[i] = *(const short8*)&As[(wy * 64 + i * 16 + l15) * 32 + lq * 8];
    #pragma unroll
    for (int j = 0; j < 4; ++j)
      b[j] = *(const short8*)&Bs[(wx * 64 + j * 16 + l15) * 32 + lq * 8];
    #pragma unroll
    for (int i = 0; i < 4; ++i)
      #pragma unroll
      for (int j = 0; j < 4; ++j)
        acc[i][j] = __builtin_amdgcn_mfma_f32_16x16x32_bf16(a[i], b[j], acc[i][j], 0, 0, 0);
  }
  #pragma unroll
  for (int i = 0; i < 4; ++i)
    #pragma unroll
    for (int j = 0; j < 4; ++j)
      #pragma unroll
      for (int r = 0; r < 4; ++r) {
        const int row = bm * 128 + wy * 64 + i * 16 + lq * 4 + r;
        const int col = bn * 128 + wx * 64 + j * 16 + l15;
        float v = acc[i][j][r];
        if (RELU) v = fmaxf(v, 0.0f);
        cstore(C + (size_t)row * ldc + col, v);
      }
}

// --------------------------- weight transpose fp32 -> bf16^T ---------------
__global__ __launch_bounds__(256) void transpose_bf_k(const float* __restrict__ src,
                                                      u16* __restrict__ dst,
                                                      int R, int C) {
  __shared__ float tile[32][33];
  const int tid = threadIdx.x;
  const size_t zoff = (size_t)blockIdx.z * R * C;
  const int r0 = blockIdx.y * 32, c0 = blockIdx.x * 32;
  const int tx = tid & 31, ty = tid >> 5;
  #pragma unroll
  for (int i = 0; i < 4; ++i)
    tile[ty + i * 8][tx] = src[zoff + (size_t)(r0 + ty + i * 8) * C + c0 + tx];
  __syncthreads();
  #pragma unroll
  for (int i = 0; i < 4; ++i)
    dst[zoff + (size_t)(c0 + ty + i * 8) * R + r0 + tx] = f2bf(tile[tx][ty + i * 8]);
}

// --------------------------- final combine ---------------------------------
__global__ __launch_bounds__(256) void combine_k(const float* __restrict__ x2,
                                                 const float* __restrict__ ye,
                                                 const int*   __restrict__ tok_e,
                                                 const float* __restrict__ tok_g,
                                                 const int*   __restrict__ tok_p,
                                                 float* __restrict__ out) {
  const int t = blockIdx.x, tid = threadIdx.x;
  float4 v = ((const float4*)(x2 + (size_t)t * D_))[tid];
  #pragma unroll
  for (int r = 0; r < 2; ++r) {
    const int p = tok_p[2 * t + r];
    if (p >= 0) {
      const int e = tok_e[2 * t + r];
      const float g = tok_g[2 * t + r];
      const float4 y = ((const float4*)(ye + (size_t)(e * CAP_ + p) * D_))[tid];
      v.x = fmaf(g, y.x, v.x);
      v.y = fmaf(g, y.y, v.y);
      v.z = fmaf(g, y.z, v.z);
      v.w = fmaf(g, y.w, v.w);
    }
  }
  ((float4*)(out + (size_t)t * D_))[tid] = v;
}

// ---------------------------------------------------------------------------
extern "C" void kernel_launch(void* const* d_in, const int* in_sizes, int n_in,
                              void* d_out, int out_size, void* d_ws, size_t ws_size,
                              hipStream_t stream) {
  const float* x    = (const float*)d_in[0];
  const float* g1   = (const float*)d_in[1];
  const float* wqkv = (const float*)d_in[2];
  const float* wo   = (const float*)d_in[3];
  const float* g2   = (const float*)d_in[4];
  const float* wr   = (const float*)d_in[5];
  const float* w1   = (const float*)d_in[6];
  const float* w2   = (const float*)d_in[7];
  float* out = (float*)d_out;
  char* ws = (char*)d_ws;
  const size_t MB = 1ull << 20;

  // Phase-aliased workspace layout (~233 MB):
  u16*   y1hh  = (u16*)  (ws + 0);          // 8MB  fp16-hi of rmsnorm1 out; reused as qhi
  u16*   y1hl  = (u16*)  (ws + 8 * MB);     // 8MB  fp16-lo; reused as qlo
  u16*   ahh   = (u16*)  (ws + 16 * MB);    // 8MB  attn out fp16-hi
  u16*   ahl   = (u16*)  (ws + 24 * MB);    // 8MB  attn out fp16-lo
  u16*   hbf   = (u16*)  (ws + 0);          // 40MB MoE hidden (aliases the above)
  float* qkv   = (float*)(ws + 40 * MB);    // 48MB, dead after rope/v pack
  float* PO    = (float*)(ws + 40 * MB);    // 16.8MB attn split-K partials (after vpack)
  float* Pm    = (float*)(ws + 58 * MB);    // 0.26MB
  float* Pl2   = (float*)(ws + 59 * MB);    // 0.26MB
  u16*   xe    = (u16*)  (ws + 40 * MB);    // 20MB, aliases qkv/PO (MoE time)
  float* x2    = (float*)(ws + 88 * MB);    // 16MB
  float* y2    = (float*)(ws + 104 * MB);   // 16MB (fp32 for router!)
  u16*   y2b   = (u16*)  (ws + 120 * MB);   // 8MB
  u16*   w1t   = (u16*)  (ws + 128 * MB);   // 32MB  [E][FFN][D] bf16
  u16*   w2t   = (u16*)  (ws + 160 * MB);   // 32MB  [E][D][FFN] bf16
  float* ye    = (float*)(ws + 192 * MB);   // 40MB (MoE time)
  u16*   wqh   = (u16*)  (ws + 192 * MB);   // 6MB  w_qkv^T fp16-hi (dead before rope)
  u16*   wql   = (u16*)  (ws + 198 * MB);   // 6MB  fp16-lo
  u16*   khi   = (u16*)  (ws + 192 * MB);   // 8MB  (after QKV gemm)
  u16*   klo   = (u16*)  (ws + 200 * MB);   // 8MB
  u16*   vpk   = (u16*)  (ws + 208 * MB);   // 16MB packed V fp16 hi/lo
  u16*   woh   = (u16*)  (ws + 224 * MB);   // 2MB  w_o^T fp16-hi (dead before MoE ye)
  u16*   wol   = (u16*)  (ws + 226 * MB);   // 2MB
  int*   cnt   = (int*)  (ws + 232 * MB);
  int*   tok_e = cnt + 16;                  // 2*T
  float* tok_g = (float*)(tok_e + 2 * T_);  // 2*T
  int*   tok_p = (int*)  (tok_g + 2 * T_);  // 2*T
  int*   etok  = tok_p + 2 * T_;            // E*CAP

  init_k<<<1, 64, 0, stream>>>(cnt);
  transpose_bf_k<<<dim3(FFN_/32, D_/32, E_), 256, 0, stream>>>(w1, w1t, D_, FFN_);
  transpose_bf_k<<<dim3(D_/32, FFN_/32, E_), 256, 0, stream>>>(w2, w2t, FFN_, D_);
  // w_qkv (Dx3D) -> [3D][D] fp16 hi/lo; w_o (DxD) -> [D][D] fp16 hi/lo
  wsplit_t_k<<<dim3(3*D_/32, D_/32), 256, 0, stream>>>(wqkv, wqh, wql, D_, 3*D_);
  wsplit_t_k<<<dim3(D_/32, D_/32), 256, 0, stream>>>(wo, woh, wol, D_, D_);

  // x -> rmsnorm -> y1 (fp16 hi/lo only)
  rmsnorm_k<<<T_, 256, 0, stream>>>(x, g1, (float*)nullptr, (u16*)nullptr, y1hh, y1hl);
  // qkv = y1 @ w_qkv via split-fp16 MFMA (fp32 out)
  gemm_split<false><<<dim3(3 * D_ / 128, T_ / 128), 256, 0, stream>>>(
      y1hh, y1hl, wqh, wql, nullptr, qkv, D_, D_, D_, 3 * D_);
  // RoPE + split q,k (q pre-scaled by 1/8); y1hh/y1hl are dead -> reuse as qhi/qlo
  ropesplit_k<<<T_ * H_ * 32 / 256, 256, 0, stream>>>(qkv, y1hh, y1hl, khi, klo);
  // V -> packed fp16 hi/lo B-operand layout
  vpack_k<<<dim3(S_ / 64, B_ * H_), 256, 0, stream>>>(qkv, vpk);
  // MFMA flash attention (split-K, chained PV) -> fp16 hi/lo + partials
  attn_mfma_k<<<dim3(48, B_ * H_), 256, 0, stream>>>(
      y1hh, y1hl, khi, klo, vpk, ahh, ahl, PO, Pm, Pl2);
  attn_combine_k<<<dim3(16, B_ * H_), 256, 0, stream>>>(PO, Pm, Pl2, ahh, ahl);
  // x2 = attn @ w_o + x via split-fp16 MFMA
  gemm_split<true><<<dim3(D_ / 128, T_ / 128), 256, 0, stream>>>(
      ahh, ahl, woh, wol, x, x2, D_, D_, D_, D_);
  // x2 -> rmsnorm -> y2 (fp32) + y2b (bf16)
  rmsnorm_k<<<T_, 256, 0, stream>>>(x2, g2, y2, y2b, (u16*)nullptr, (u16*)nullptr);
  // router (fp32 logits, top-2, capacity assignment)
  router_k<<<T_ / 4, 256, 0, stream>>>(y2, wr, cnt, tok_e, tok_g, tok_p, etok);
  // gather per-expert token rows (bf16)
  gather_k<<<dim3(CAP_, E_), 256, 0, stream>>>(y2b, etok, cnt, xe);
  // h = relu(xe @ w1) (bf16 out), batched over experts
  gemm_bt<u16, true><<<dim3(FFN_/128, CAP_/128, E_), 256, 0, stream>>>(
      xe, w1t, hbf, CAP_, FFN_, D_, D_, D_, FFN_,
      (long)CAP_ * D_, (long)FFN_ * D_, (long)CAP_ * FFN_);
  // ye = h @ w2 (fp32 out)
  gemm_bt<float, false><<<dim3(D_/128, CAP_/128, E_), 256, 0, stream>>>(
      hbf, w2t, ye, CAP_, D_, FFN_, FFN_, FFN_, D_,
      (long)CAP_ * FFN_, (long)D_ * FFN_, (long)CAP_ * D_);
  // out = x2 + sum_r gate_r * ye[...]
  combine_k<<<T_, 256, 0, stream>>>(x2, ye, tok_e, tok_g, tok_p, out);
}